// Round 1
// baseline (3703.901 us; speedup 1.0000x reference)
//
#include <hip/hip_runtime.h>
#include <math.h>

// ---------------------------------------------------------------------------
// ImitateJoint: 12-step beam-search LSTM decoder.
// B=64 images, K=8 beams (BK=512 rows), T=12, H=2048, IN=2048, D=400, E=128.
// Round 3: GEMMs on the matrix pipe via f16-split (hi + 2^-11*lo') with dual
// fp32 MFMA accumulators -> ~fp32 accuracy at ~650 TF f32-equiv peak.
// Decision-critical math (softmax, Gumbel g, top-k, entropy) stays fp64.
// ---------------------------------------------------------------------------

#define BB   64
#define KK   8
#define TT   12
#define HH   2048
#define DD   400
#define EE   128
#define BKR  512          // B*K rows
#define G4   8192         // 4*H

// ---- workspace layout (byte offsets) --------------------------------------
static const size_t OFF_STATE = 0;                // doubles, 14272 used
static const size_t OFF_H     = 114688;           // float [512][2048]
static const size_t OFF_C     = 4308992;          // float [512][2048]
static const size_t ZERO_END  = 8503296;          // memset 0 .. here
static const size_t OFF_Z     = 8503296;          // float, 2*512*8192 partials
static const size_t OFF_H2    = 42057728;         // float [512][2048]
static const size_t OFF_C2    = 46252032;         // float [512][2048]
static const size_t OFF_HD    = 50446336;         // float [512][2048]
static const size_t OFF_EMB   = 54640640;         // float [512][128]
static const size_t OFF_XFW   = 54902784;         // float [64][8192]
static const size_t OFF_BIAS  = 56999936;         // float [8192]
static const size_t OFF_LPT   = 57032704;         // double [512][400]
static const size_t OFF_GMAT  = 58671104;         // double [512][400]
static const size_t OFF_INTS  = 60309504;         // int [1024]
static const size_t WS_TOTAL  = 60313600;         // ~57.5 MB

#define SI_G    0
#define SI_LOGP 512
#define SI_SAMP 1024
#define SI_OUTS 7168
#define SI_ENT  13312
#define SI_WPQ  13376
#define SI_LGP  13824

using half8  = __attribute__((ext_vector_type(8))) _Float16;
using floatx4 = __attribute__((ext_vector_type(4))) float;

// ---------------------------------------------------------------------------
// MFMA f16-split GEMM: C[z][512][N] = A[512,K]*B[N,K]^T partials.
// Block 256 thr = 4 waves; block tile 128x128; wave tile 64x64 = 4x4 of
// 16x16x32 MFMA; K-chunks of 32. LDS: hi/lo planes in fragment-linear order
// (slot swizzle: conflict-free reads, <=2-way writes). Register-prefetch of
// next chunk's globals overlaps VMEM latency with MFMA.
// z = acc1 + acc2/2048, acc1 = hi*hi, acc2 = hi*lo' + lo'*hi, lo' = 2048*lo.
// A: up to 3 concatenated f32 segments; B: up to 2 (weights are N-major).
// ---------------------------------------------------------------------------
__global__ __launch_bounds__(256, 2)
void ij_gemm_f16x3(const float* __restrict__ A0, const float* __restrict__ A1,
                   const float* __restrict__ A2, int kA1, int kA2,
                   int lda0, int lda1, int lda2,
                   const float* __restrict__ B0, const float* __restrict__ B1,
                   int kB1, int ldb0, int ldb1,
                   float* __restrict__ C, int N, int Klen)
{
    // 32 KB: A_hi[512] A_lo[512] B_hi[512] B_lo[512] half8-chunks
    __shared__ half8 lds[2048];

    const int tid = threadIdx.x;
    const int n0  = blockIdx.x * 128;
    const int m0  = blockIdx.y * 128;
    const int kstart = blockIdx.z * Klen;
    const int nch = Klen / 32;
    float* Cout = C + (size_t)blockIdx.z * ((size_t)512 * (size_t)N);

    const int wid    = tid >> 6;
    const int wave_m = wid & 1;          // 0..1
    const int wave_n = wid >> 1;         // 0..1
    const int lane   = tid & 63;
    const int lo16   = lane & 15;        // m/n within 16-tile (and C col)
    const int oq     = lane >> 4;        // k-octet (and C row quad)
    const int laneSlot = oq * 16 + ((lo16 + 4 * oq) & 15);   // swizzled chunk

    // staging assignment: unit u = i*256+tid; row=u>>2 (0..127), o=u&3
    const int st_o   = tid & 3;
    const int st_row0 = tid >> 2;        // +64*i
    const int st_slot = ((st_row0 & 15) + 4 * st_o) & 15;    // r part; +o*16

    float4 pfA[2][2], pfB[2][2];

    auto loadGlobals = [&](int c) {
        const int kb = kstart + c * 32;
#pragma unroll
        for (int i = 0; i < 2; ++i) {
            const int row = st_row0 + i * 64;
            const int kc  = kb + st_o * 8;
            const float* ap; int ao, ld;
            if (kc < kA1)      { ap = A0; ao = kc;       ld = lda0; }
            else if (kc < kA2) { ap = A1; ao = kc - kA1; ld = lda1; }
            else               { ap = A2; ao = kc - kA2; ld = lda2; }
            const float* p = ap + (size_t)(m0 + row) * ld + ao;
            pfA[i][0] = *(const float4*)(p);
            pfA[i][1] = *(const float4*)(p + 4);
            const int bn = n0 + row;
            const float* bp; int bo, bld;
            if (kc < kB1) { bp = B0; bo = kc;       bld = ldb0; }
            else          { bp = B1; bo = kc - kB1; bld = ldb1; }
            if (bn < N) {
                const float* q = bp + (size_t)bn * bld + bo;
                pfB[i][0] = *(const float4*)(q);
                pfB[i][1] = *(const float4*)(q + 4);
            } else {
                pfB[i][0] = make_float4(0.f,0.f,0.f,0.f);
                pfB[i][1] = make_float4(0.f,0.f,0.f,0.f);
            }
        }
    };

    auto writeLDS = [&]() {
#pragma unroll
        for (int i = 0; i < 2; ++i) {
            const int row = st_row0 + i * 64;
            const int mt  = row >> 4;
            const int idx = mt * 64 + st_o * 16 + (((row & 15) + 4 * st_o) & 15);
            // A
            {
                float x[8] = {pfA[i][0].x, pfA[i][0].y, pfA[i][0].z, pfA[i][0].w,
                              pfA[i][1].x, pfA[i][1].y, pfA[i][1].z, pfA[i][1].w};
                half8 hi8, lo8;
#pragma unroll
                for (int j = 0; j < 8; ++j) {
                    _Float16 h = (_Float16)x[j];
                    hi8[j] = h;
                    lo8[j] = (_Float16)((x[j] - (float)h) * 2048.0f);
                }
                lds[idx]       = hi8;
                lds[512 + idx] = lo8;
            }
            // B
            {
                float x[8] = {pfB[i][0].x, pfB[i][0].y, pfB[i][0].z, pfB[i][0].w,
                              pfB[i][1].x, pfB[i][1].y, pfB[i][1].z, pfB[i][1].w};
                half8 hi8, lo8;
#pragma unroll
                for (int j = 0; j < 8; ++j) {
                    _Float16 h = (_Float16)x[j];
                    hi8[j] = h;
                    lo8[j] = (_Float16)((x[j] - (float)h) * 2048.0f);
                }
                lds[1024 + idx] = hi8;
                lds[1536 + idx] = lo8;
            }
        }
    };

    floatx4 acc1[4][4], acc2[4][4];
#pragma unroll
    for (int i = 0; i < 4; ++i)
#pragma unroll
        for (int j = 0; j < 4; ++j) { acc1[i][j] = (floatx4)0.f; acc2[i][j] = (floatx4)0.f; }

    loadGlobals(0);
    for (int c = 0; c < nch; ++c) {
        __syncthreads();               // prior chunk's fragment reads complete
        writeLDS();
        __syncthreads();
        if (c + 1 < nch) loadGlobals(c + 1);

        half8 Ahi[4], Alo[4];
#pragma unroll
        for (int mt = 0; mt < 4; ++mt) {
            const int amt = wave_m * 4 + mt;
            Ahi[mt] = lds[amt * 64 + laneSlot];
            Alo[mt] = lds[512 + amt * 64 + laneSlot];
        }
#pragma unroll
        for (int nt = 0; nt < 4; ++nt) {
            const int bnt = wave_n * 4 + nt;
            half8 Bhi = lds[1024 + bnt * 64 + laneSlot];
            half8 Blo = lds[1536 + bnt * 64 + laneSlot];
#pragma unroll
            for (int mt = 0; mt < 4; ++mt) {
                acc1[mt][nt] = __builtin_amdgcn_mfma_f32_16x16x32_f16(Ahi[mt], Bhi, acc1[mt][nt], 0, 0, 0);
                acc2[mt][nt] = __builtin_amdgcn_mfma_f32_16x16x32_f16(Ahi[mt], Blo, acc2[mt][nt], 0, 0, 0);
                acc2[mt][nt] = __builtin_amdgcn_mfma_f32_16x16x32_f16(Alo[mt], Bhi, acc2[mt][nt], 0, 0, 0);
            }
        }
    }

    // epilogue: C row = m0+wave_m*64+mt*16+oq*4+v, col = n0+wave_n*64+nt*16+lo16
    const float s = 1.0f / 2048.0f;
#pragma unroll
    for (int mt = 0; mt < 4; ++mt) {
        const int rbase = m0 + wave_m * 64 + mt * 16 + oq * 4;
#pragma unroll
        for (int nt = 0; nt < 4; ++nt) {
            const int col = n0 + wave_n * 64 + nt * 16 + lo16;
            if (col >= N) continue;
#pragma unroll
            for (int v = 0; v < 4; ++v) {
                float val = acc1[mt][nt][v] + acc2[mt][nt][v] * s;
                Cout[(size_t)(rbase + v) * N + col] = val;
            }
        }
    }
}

// ---------------------------------------------------------------------------
// fp32 vector GEMM (kept for the one-time xfW precompute, M=64).
// ---------------------------------------------------------------------------
#define FBM 128
#define FBN 64
#define FBK 16

__global__ __launch_bounds__(256, 2)
void ij_gemm_f32(const float* __restrict__ A0, const float* __restrict__ A1,
                 const float* __restrict__ A2, int kA1, int kA2,
                 int lda0, int lda1, int lda2,
                 const float* __restrict__ B0, const float* __restrict__ B1,
                 int kB1, int ldb0, int ldb1,
                 float* __restrict__ C, int M, int N, int Klen)
{
    __shared__ float As[2][FBK][FBM];
    __shared__ float Bs[2][FBK][FBN];

    const int tid = threadIdx.x;
    const int tx  = tid & 15;
    const int ty  = tid >> 4;
    const int n0  = blockIdx.x * FBN;
    const int m0  = blockIdx.y * FBM;
    const int kstart = blockIdx.z * Klen;
    const int nch = Klen / FBK;
    float* Cout = C + (size_t)blockIdx.z * ((size_t)M * (size_t)N);

    const int srow = tid >> 2;
    const int kq   = tid & 3;

    float4 aR0, aR1, bR;

    auto loadChunk = [&](int kb0) {
        const int kc = kb0 + kq * 4;
        const float* ap; int ao, ld;
        if (kc < kA1)      { ap = A0; ao = kc;       ld = lda0; }
        else if (kc < kA2) { ap = A1; ao = kc - kA1; ld = lda1; }
        else               { ap = A2; ao = kc - kA2; ld = lda2; }
        const int r0 = m0 + srow, r1 = r0 + 64;
        aR0 = (r0 < M) ? *(const float4*)(ap + (size_t)r0 * ld + ao)
                       : make_float4(0.f, 0.f, 0.f, 0.f);
        aR1 = (r1 < M) ? *(const float4*)(ap + (size_t)r1 * ld + ao)
                       : make_float4(0.f, 0.f, 0.f, 0.f);
        const float* bp; int bo, bld;
        if (kc < kB1) { bp = B0; bo = kc;       bld = ldb0; }
        else          { bp = B1; bo = kc - kB1; bld = ldb1; }
        const int bn = n0 + srow;
        bR = (bn < N) ? *(const float4*)(bp + (size_t)bn * bld + bo)
                      : make_float4(0.f, 0.f, 0.f, 0.f);
    };
    auto storeChunk = [&](int bsel) {
        const int k4 = kq * 4;
        As[bsel][k4+0][srow]      = aR0.x;
        As[bsel][k4+1][srow]      = aR0.y;
        As[bsel][k4+2][srow]      = aR0.z;
        As[bsel][k4+3][srow]      = aR0.w;
        As[bsel][k4+0][srow + 64] = aR1.x;
        As[bsel][k4+1][srow + 64] = aR1.y;
        As[bsel][k4+2][srow + 64] = aR1.z;
        As[bsel][k4+3][srow + 64] = aR1.w;
        Bs[bsel][k4+0][srow]      = bR.x;
        Bs[bsel][k4+1][srow]      = bR.y;
        Bs[bsel][k4+2][srow]      = bR.z;
        Bs[bsel][k4+3][srow]      = bR.w;
    };

    float acc[8][4];
#pragma unroll
    for (int i = 0; i < 8; ++i)
#pragma unroll
        for (int j = 0; j < 4; ++j) acc[i][j] = 0.f;

    loadChunk(kstart);
    storeChunk(0);
    __syncthreads();
    int bsel = 0;
    for (int c = 0; c < nch; ++c) {
        if (c + 1 < nch) loadChunk(kstart + (c + 1) * FBK);
#pragma unroll
        for (int kkk = 0; kkk < FBK; ++kkk) {
            float a[8], b[4];
            const float4 av0 = *(const float4*)&As[bsel][kkk][ty * 8];
            const float4 av1 = *(const float4*)&As[bsel][kkk][ty * 8 + 4];
            a[0]=av0.x; a[1]=av0.y; a[2]=av0.z; a[3]=av0.w;
            a[4]=av1.x; a[5]=av1.y; a[6]=av1.z; a[7]=av1.w;
            const float2 bv0 = *(const float2*)&Bs[bsel][kkk][tx * 2];
            const float2 bv1 = *(const float2*)&Bs[bsel][kkk][tx * 2 + 32];
            b[0]=bv0.x; b[1]=bv0.y; b[2]=bv1.x; b[3]=bv1.y;
#pragma unroll
            for (int i = 0; i < 8; ++i)
#pragma unroll
                for (int j = 0; j < 4; ++j)
                    acc[i][j] = fmaf(a[i], b[j], acc[i][j]);
        }
        if (c + 1 < nch) storeChunk(bsel ^ 1);
        __syncthreads();
        bsel ^= 1;
    }

#pragma unroll
    for (int i = 0; i < 8; ++i) {
        const int row = m0 + ty * 8 + i;
        if (row >= M) continue;
        const size_t rbase = (size_t)row * N;
#pragma unroll
        for (int g = 0; g < 2; ++g) {
            const int col = n0 + tx * 2 + g * 32;
            if (col + 1 < N) {
                float2 st; st.x = acc[i][g*2+0]; st.y = acc[i][g*2+1];
                *(float2*)(Cout + rbase + col) = st;
            } else if (col < N) {
                Cout[rbase + col] = acc[i][g*2+0];
            }
        }
    }
}

// ---------------------------------------------------------------------------
__global__ void ij_bias_kernel(const float* __restrict__ b_ih, const float* __restrict__ b_hh,
                               float* __restrict__ bias)
{
    int i = blockIdx.x * 256 + threadIdx.x;
    if (i < G4) bias[i] = b_ih[i] + b_hh[i];
}

__global__ void ij_emb_kernel(const float* __restrict__ W_emb, const float* __restrict__ b_emb,
                              const int* __restrict__ pop_t, float* __restrict__ emb)
{
    int i = blockIdx.x * 256 + threadIdx.x;
    if (i >= BKR * EE) return;
    int r = i >> 7, e = i & 127;
    float v = W_emb[e * DD + pop_t[r]] + b_emb[e];
    emb[i] = v > 0.f ? v : 0.f;
}

// LSTM elementwise; fuses gate split-K reduce + xfW row-add + bias.
__global__ void ij_lstm_kernel(const float* __restrict__ z0, const float* __restrict__ z1,
                               const float* __restrict__ xfw, const float* __restrict__ bias,
                               const float* __restrict__ c,
                               float* __restrict__ h2, float* __restrict__ c2)
{
    int i = blockIdx.x * 256 + threadIdx.x;
    if (i >= BKR * HH) return;
    int r = i >> 11, hh = i & 2047;
    const size_t zb = (size_t)r * G4;
    const float* xw = xfw + (size_t)(r & 63) * G4;
    float iv = z0[zb + hh]        + z1[zb + hh]        + xw[hh]        + bias[hh];
    float fv = z0[zb + HH + hh]   + z1[zb + HH + hh]   + xw[HH + hh]   + bias[HH + hh];
    float gv = z0[zb + 2*HH + hh] + z1[zb + 2*HH + hh] + xw[2*HH + hh] + bias[2*HH + hh];
    float ov = z0[zb + 3*HH + hh] + z1[zb + 3*HH + hh] + xw[3*HH + hh] + bias[3*HH + hh];
    float si = 1.f / (1.f + expf(-iv));
    float sf = 1.f / (1.f + expf(-fv));
    float so = 1.f / (1.f + expf(-ov));
    float cv = sf * c[i] + si * tanhf(gv);
    c2[i] = cv;
    h2[i] = so * tanhf(cv);
}

__global__ void ij_reduce_fc1_kernel(const float* __restrict__ part, const float* __restrict__ b_fc1,
                                     float* __restrict__ hd)
{
    int i = blockIdx.x * 256 + threadIdx.x;
    if (i >= BKR * HH) return;
    float v = part[i] + part[i + 1048576] + part[i + 2097152] + part[i + 3145728]
            + b_fc1[i & 2047];
    hd[i] = v > 0.f ? v : 0.f;
}

__global__ void ij_reduce_xfw_kernel(const float* __restrict__ part, float* __restrict__ xfw)
{
    int i = blockIdx.x * 256 + threadIdx.x;
    if (i >= BB * G4) return;
    xfw[i] = part[i] + part[i + 524288] + part[i + 1048576] + part[i + 1572864];
}

// ---------------------------------------------------------------------------
// Per-row: reduce 16 logits partials + b_out + mask row, log_softmax, greedy
// argmax, Gumbel-with-max conditioned g. All f64 (decision-critical).
// ---------------------------------------------------------------------------
__global__ __launch_bounds__(256)
void ij_softmax_g_kernel(const float* __restrict__ part, const float* __restrict__ b_out,
                         const float* __restrict__ mask_table, const int* __restrict__ pop_t,
                         const float* __restrict__ gum_t, const double* __restrict__ G,
                         const double* __restrict__ logp,
                         double* __restrict__ logp_tok, double* __restrict__ gmat,
                         int* __restrict__ greedy)
{
    const int r = blockIdx.x, tid = threadIdx.x;
    __shared__ double sred[256];
    __shared__ int    sidx[256];
    __shared__ double sbc[2];

    const int pop = pop_t[r];
    const int j0 = tid, j1 = tid + 256;
    double lg0 = -INFINITY, lg1 = -INFINITY;
    if (j0 < DD) {
        double v = (double)b_out[j0] + (double)mask_table[pop * DD + j0];
#pragma unroll
        for (int s = 0; s < 16; ++s) v += (double)part[(size_t)s * (BKR*DD) + (size_t)r * DD + j0];
        lg0 = v;
    }
    if (j1 < DD) {
        double v = (double)b_out[j1] + (double)mask_table[pop * DD + j1];
#pragma unroll
        for (int s = 0; s < 16; ++s) v += (double)part[(size_t)s * (BKR*DD) + (size_t)r * DD + j1];
        lg1 = v;
    }
    double mv = lg0; int mi = j0;
    if (lg1 > mv) { mv = lg1; mi = j1; }
    sred[tid] = mv; sidx[tid] = mi;
    __syncthreads();
    for (int off = 128; off > 0; off >>= 1) {
        if (tid < off) {
            double ov = sred[tid+off]; int oi = sidx[tid+off];
            if (ov > sred[tid] || (ov == sred[tid] && oi < sidx[tid])) { sred[tid] = ov; sidx[tid] = oi; }
        }
        __syncthreads();
    }
    if (tid == 0) { sbc[0] = sred[0]; greedy[r] = sidx[0]; }
    __syncthreads();
    const double rowmax = sbc[0];

    double es = 0.0;
    if (j0 < DD) es += exp(lg0 - rowmax);
    if (j1 < DD) es += exp(lg1 - rowmax);
    __syncthreads();
    sred[tid] = es;
    __syncthreads();
    for (int off = 128; off > 0; off >>= 1) {
        if (tid < off) sred[tid] += sred[tid+off];
        __syncthreads();
    }
    if (tid == 0) sbc[1] = log(sred[0]);
    __syncthreads();
    const double lse = sbc[1];
    const double lpr = logp[r], Gr = G[r];

    double gp0 = -INFINITY, gp1 = -INFINITY;
    if (j0 < DD) {
        double lt = lg0 - rowmax - lse;
        logp_tok[(size_t)r * DD + j0] = lt;
        double u = (double)gum_t[(size_t)r * DD + j0];
        u = fmin(fmax(u, 1e-9), 1.0 - 1e-9);
        gp0 = lt + lpr + (-log(-log(u)));
    }
    if (j1 < DD) {
        double lt = lg1 - rowmax - lse;
        logp_tok[(size_t)r * DD + j1] = lt;
        double u = (double)gum_t[(size_t)r * DD + j1];
        u = fmin(fmax(u, 1e-9), 1.0 - 1e-9);
        gp1 = lt + lpr + (-log(-log(u)));
    }
    __syncthreads();
    sred[tid] = fmax(gp0, gp1);
    __syncthreads();
    for (int off = 128; off > 0; off >>= 1) {
        if (tid < off) sred[tid] = fmax(sred[tid], sred[tid+off]);
        __syncthreads();
    }
    const double Z = sred[0];
    if (j0 < DD) {
        double v = Gr - gp0 + log1p(-exp(gp0 - Z));
        gmat[(size_t)r * DD + j0] = Gr - fmax(v, 0.0) - log1p(exp(-fabs(v)));
    }
    if (j1 < DD) {
        double v = Gr - gp1 + log1p(-exp(gp1 - Z));
        gmat[(size_t)r * DD + j1] = Gr - fmax(v, 0.0) - log1p(exp(-fabs(v)));
    }
}

// ---------------------------------------------------------------------------
// One block per image b: top-8 of 3200 (desc, low index on tie), bookkeeping.
// ---------------------------------------------------------------------------
__global__ __launch_bounds__(256)
void ij_beam_kernel(const double* __restrict__ gmat, const double* __restrict__ logp_tok,
                    const int* __restrict__ greedy, const int* __restrict__ pop_t,
                    const float* __restrict__ mask_table,
                    double* __restrict__ G, double* __restrict__ logp,
                    double* __restrict__ samples, double* __restrict__ outs,
                    double* __restrict__ entacc, double* __restrict__ wpq,
                    double* __restrict__ lgp_o, int* __restrict__ order_g, int t)
{
    const int b = blockIdx.x, tid = threadIdx.x;
    __shared__ double sv[256];
    __shared__ int    si2[256];
    __shared__ double gval8[8];
    __shared__ int    gidx8[8];
    __shared__ int    ord8[8], smp8[8];
    __shared__ double lp28[8], sel8[8], Gn8[8];
    __shared__ double oldS[8][TT], oldO[8][TT];
    __shared__ double efull[8];

    if (t > 0) {
        for (int pass = 0; pass < 8; ++pass) {
            double bv = -INFINITY; int bi = 0x7fffffff;
            for (int cand = tid; cand < KK * DD; cand += 256) {
                bool used = false;
                for (int p = 0; p < pass; ++p) used |= (gidx8[p] == cand);
                if (used) continue;
                int kb2 = cand / DD, d = cand - kb2 * DD;
                double v = gmat[(size_t)(kb2 * BB + b) * DD + d];
                if (v > bv || (v == bv && cand < bi)) { bv = v; bi = cand; }
            }
            sv[tid] = bv; si2[tid] = bi;
            __syncthreads();
            for (int off = 128; off > 0; off >>= 1) {
                if (tid < off) {
                    double ov = sv[tid+off]; int oi = si2[tid+off];
                    if (ov > sv[tid] || (ov == sv[tid] && oi < si2[tid])) { sv[tid] = ov; si2[tid] = oi; }
                }
                __syncthreads();
            }
            if (tid == 0) { gval8[pass] = sv[0]; gidx8[pass] = si2[0]; }
            __syncthreads();
        }
    }

    if (tid < 8) {
        const int s = tid, rp = s * BB + b;
        int ord, smp; double Gn;
        if (t == 0) { ord = rp; smp = greedy[rp]; Gn = G[rp]; }
        else {
            int idx = gidx8[s]; int kb2 = idx / DD;
            ord = kb2 * BB + b; smp = idx - kb2 * DD; Gn = gval8[s];
        }
        ord8[s] = ord; smp8[s] = smp; Gn8[s] = Gn;
        double sel = logp_tok[(size_t)ord * DD + smp];
        double lp2 = (t == 0) ? logp[ord] : logp[ord] + sel;
        sel8[s] = sel; lp28[s] = lp2;
    }
    __syncthreads();
    if (tid < 8 * TT) {
        int s = tid / TT, ttc = tid - s * TT;
        oldS[s][ttc] = samples[ord8[s] * TT + ttc];
        oldO[s][ttc] = outs[ord8[s] * TT + ttc];
    }
    __syncthreads();
    if (tid < 8 * TT) {
        int s = tid / TT, ttc = tid - s * TT;
        int rp = s * BB + b;
        samples[rp * TT + ttc] = (ttc == t) ? (double)smp8[s] : oldS[s][ttc];
        outs[rp * TT + ttc]    = (ttc == t) ? sel8[s]         : oldO[s][ttc];
    }
    if (tid >= 96 && tid < 104) {
        int s = tid - 96, rp = s * BB + b;
        G[rp]       = Gn8[s];
        logp[rp]    = lp28[s];
        order_g[rp] = ord8[s];
    }

    if (t > 0) {
        for (int s = 0; s < KK - 1; ++s) {
            const int ord = ord8[s];
            const double* lrow = logp_tok + (size_t)ord * DD;
            const float*  mrow = mask_table + (size_t)pop_t[ord] * DD;
            double acc = 0.0;
            for (int j = tid; j < DD; j += 256) {
                double lp_ = lrow[j];
                if (mrow[j] == 0.0f) acc += lp_ * exp(lp_);
            }
            __syncthreads();
            sv[tid] = acc;
            __syncthreads();
            for (int off = 128; off > 0; off >>= 1) {
                if (tid < off) sv[tid] += sv[tid+off];
                __syncthreads();
            }
            if (tid == 0) efull[s] = sv[0];
            __syncthreads();
        }
        if (tid == 0) {
            const double gk = gval8[7];
            double sw = 0.0, swe = 0.0;
            for (int s = 0; s < KK - 1; ++s) {
                double phi = lp28[s];
                double x = gk - phi;
                double y = exp(-x);
                double gls;
                if (x >= 10.0) gls = -x - y * 0.5 + y * y * (1.0 / 24.0);
                else           gls = log(-expm1(-exp(-fmin(x, 10.0))));
                double w = exp(phi - gls);
                wpq[b * (KK-1) + s]   = w;
                lgp_o[b * (KK-1) + s] = phi;
                sw += w; swe += w * efull[s];
            }
            entacc[b] += swe / sw;
        }
    }
}

__global__ void ij_permute_kernel(const float* __restrict__ h2, const float* __restrict__ c2,
                                  const int* __restrict__ order_g,
                                  float* __restrict__ h, float* __restrict__ c)
{
    int i = blockIdx.x * 256 + threadIdx.x;
    if (i >= BKR * HH) return;
    int r = i >> 11, j = i & 2047;
    int o = order_g[r];
    h[i] = h2[(size_t)o * HH + j];
    c[i] = c2[(size_t)o * HH + j];
}

__global__ void ij_final_kernel(const double* __restrict__ outs, const double* __restrict__ samples,
                                const double* __restrict__ entacc, const double* __restrict__ wpq,
                                const double* __restrict__ lgp_o, float* __restrict__ out)
{
    int i = blockIdx.x * 256 + threadIdx.x;
    if (i < 5376) {
        int bb = i / 84, rest = i - bb * 84;
        int s = rest / TT, ttc = rest - s * TT;
        size_t src = (size_t)(s * BB + bb) * TT + ttc;
        out[i]        = (float)outs[src];
        out[5376 + i] = (float)samples[src];
    } else if (i < 5440) {
        out[10752 + (i - 5376)] = (float)entacc[i - 5376];
    } else if (i < 5888) {
        int q = i - 5440; out[10816 + q] = (float)wpq[q];
    } else if (i < 6336) {
        int q = i - 5888; out[11264 + q] = (float)lgp_o[q];
    }
}

// ---------------------------------------------------------------------------
extern "C" void kernel_launch(void* const* d_in, const int* in_sizes, int n_in,
                              void* d_out, int out_size, void* d_ws, size_t ws_size,
                              hipStream_t stream)
{
    const float* x_f   = (const float*)d_in[0];
    const float* x_f3  = (const float*)d_in[1];
    const float* gum   = (const float*)d_in[2];
    const int*   pop   = (const int*)d_in[3];
    const float* mask  = (const float*)d_in[4];
    const float* W_emb = (const float*)d_in[5];
    const float* b_emb = (const float*)d_in[6];
    const float* W_ih  = (const float*)d_in[7];
    const float* W_hh  = (const float*)d_in[8];
    const float* b_ih  = (const float*)d_in[9];
    const float* b_hh  = (const float*)d_in[10];
    const float* W_fc1 = (const float*)d_in[11];
    const float* b_fc1 = (const float*)d_in[12];
    const float* W_out = (const float*)d_in[13];
    const float* b_out = (const float*)d_in[14];
    float* out = (float*)d_out;
    char*  ws  = (char*)d_ws;

    if (ws_size < WS_TOTAL) return;

    double* STATE = (double*)(ws + OFF_STATE);
    double* Gv    = STATE + SI_G;
    double* LOGP  = STATE + SI_LOGP;
    double* SAMP  = STATE + SI_SAMP;
    double* OUTS  = STATE + SI_OUTS;
    double* ENT   = STATE + SI_ENT;
    double* WPQ   = STATE + SI_WPQ;
    double* LGP   = STATE + SI_LGP;
    float*  H     = (float*)(ws + OFF_H);
    float*  Cc    = (float*)(ws + OFF_C);
    float*  Z     = (float*)(ws + OFF_Z);
    float*  Z1    = Z + (size_t)BKR * G4;
    float*  H2    = (float*)(ws + OFF_H2);
    float*  C2    = (float*)(ws + OFF_C2);
    float*  HD    = (float*)(ws + OFF_HD);
    float*  EMB   = (float*)(ws + OFF_EMB);
    float*  XFW   = (float*)(ws + OFF_XFW);
    float*  BIAS  = (float*)(ws + OFF_BIAS);
    double* LPT   = (double*)(ws + OFF_LPT);
    double* GMAT  = (double*)(ws + OFF_GMAT);
    int*    ORDER = (int*)(ws + OFF_INTS);
    int*    GREEDY= ORDER + 512;

    hipMemsetAsync(ws, 0, ZERO_END, stream);
    ij_bias_kernel<<<32, 256, 0, stream>>>(b_ih, b_hh, BIAS);

    // xfW = x_f @ W_ih[:, :2048]^T  (one-time, fp32 vector GEMM, M=64)
    ij_gemm_f32<<<dim3(128, 1, 4), 256, 0, stream>>>(
        x_f, nullptr, nullptr, 1 << 30, 1 << 30, 2048, 0, 0,
        W_ih, nullptr, 1 << 30, 4224, 0,
        Z, BB, G4, 512);
    ij_reduce_xfw_kernel<<<2048, 256, 0, stream>>>(Z, XFW);

    for (int t = 0; t < TT; ++t) {
        const int* pop_t = pop + t * BKR;
        ij_emb_kernel<<<256, 256, 0, stream>>>(W_emb, b_emb, pop_t, EMB);

        // gate GEMM (MFMA f16-split): A=[emb|xf3_t|h], B=[W_ih cols 2048..|W_hh]
        // split-K=2 partials; lstm fuses reduce + xfW + bias.
        ij_gemm_f16x3<<<dim3(64, 4, 2), 256, 0, stream>>>(
            EMB, x_f3 + (size_t)t * BKR * 2048, H, 128, 2176, 128, 2048, 2048,
            W_ih + 2048, W_hh, 2176, 4224, 2048,
            Z, G4, 2112);

        ij_lstm_kernel<<<4096, 256, 0, stream>>>(Z, Z1, XFW, BIAS, Cc, H2, C2);

        // fc1 (MFMA, split-K=4; reduce w/ bias+relu)
        ij_gemm_f16x3<<<dim3(16, 4, 4), 256, 0, stream>>>(
            H2, nullptr, nullptr, 1 << 30, 1 << 30, 2048, 0, 0,
            W_fc1, nullptr, 1 << 30, 2048, 0,
            Z, HH, 512);
        ij_reduce_fc1_kernel<<<4096, 256, 0, stream>>>(Z, b_fc1, HD);

        // logits (MFMA, split-K=16; reduce folded into softmax kernel)
        ij_gemm_f16x3<<<dim3(4, 4, 16), 256, 0, stream>>>(
            HD, nullptr, nullptr, 1 << 30, 1 << 30, 2048, 0, 0,
            W_out, nullptr, 1 << 30, 2048, 0,
            Z, DD, 128);

        ij_softmax_g_kernel<<<512, 256, 0, stream>>>(
            Z, b_out, mask, pop_t, gum + (size_t)t * BKR * DD,
            Gv, LOGP, LPT, GMAT, GREEDY);

        ij_beam_kernel<<<64, 256, 0, stream>>>(
            GMAT, LPT, GREEDY, pop_t, mask,
            Gv, LOGP, SAMP, OUTS, ENT, WPQ, LGP, ORDER, t);

        ij_permute_kernel<<<4096, 256, 0, stream>>>(H2, C2, ORDER, H, Cc);
    }

    ij_final_kernel<<<25, 256, 0, stream>>>(OUTS, SAMP, ENT, WPQ, LGP, out);
    (void)in_sizes; (void)n_in; (void)out_size;
}

// Round 3
// 3334.218 us; speedup vs baseline: 1.1109x; 1.1109x over previous
//
#include <hip/hip_runtime.h>
#include <math.h>

// ---------------------------------------------------------------------------
// ImitateJoint: 12-step beam-search LSTM decoder.
// B=64 images, K=8 beams (BK=512 rows), T=12, H=2048, IN=2048, D=400, E=128.
// Round 5: pre-split f16 hi/lo planes (weights once, activations fused into
// producers) + global_load_lds staging GEMM (m97 structure). Falls back to
// the round-3 reg-staging path if the workspace is too small.
// Decision-critical math (softmax, Gumbel g, top-k, entropy) stays fp64.
// ---------------------------------------------------------------------------

#define BB   64
#define KK   8
#define TT   12
#define HH   2048
#define DD   400
#define EE   128
#define BKR  512          // B*K rows
#define G4   8192         // 4*H

// ---- OLD (fallback) workspace layout (byte offsets) -----------------------
static const size_t OFF_STATE = 0;                // doubles, 14272 used
static const size_t OFF_H     = 114688;           // float [512][2048]
static const size_t OFF_C     = 4308992;          // float [512][2048]
static const size_t ZERO_END  = 8503296;          // memset 0 .. here
static const size_t OFF_Z     = 8503296;          // float, 2*512*8192 partials
static const size_t OFF_H2    = 42057728;         // float [512][2048]
static const size_t OFF_C2    = 46252032;         // float [512][2048]
static const size_t OFF_HD    = 50446336;         // float [512][2048]
static const size_t OFF_EMB   = 54640640;         // float [512][128]
static const size_t OFF_XFW   = 54902784;         // float [64][8192]
static const size_t OFF_BIAS  = 56999936;         // float [8192]
static const size_t OFF_LPT   = 57032704;         // double [512][400]
static const size_t OFF_GMAT  = 58671104;         // double [512][400]
static const size_t OFF_INTS  = 60309504;         // int [1024]
static const size_t WS_TOTAL  = 60313600;         // ~57.5 MB

// ---- NEW (pre-split) workspace layout -------------------------------------
// Pre-tiled f16 buffers: unit = half8 (16 B). Chunk tile = 1024 units:
// units [0..511] hi plane, [512..1023] lo plane; unit u = mt*64 + oq*16 + lo16
// <-> (row = blk*128 + mt*16 + lo16, k = c*32 + oq*8 + e).
static const size_t NOFF_STATE = 0;               // doubles, 14272 used
static const size_t NOFF_C     = 114688;          // float [512][2048] (cell)
static const size_t NOFF_A16H  = 4308992;         // half8 [4][64][1024] (h packed)
static const size_t NZERO_END  = 8503296;         // memset 0 .. here
static const size_t NOFF_Z     = 8503296;         // float partials (33.5 MB)
static const size_t NOFF_H2    = 42057728;        // float [512][2048]
static const size_t NOFF_C2    = 46252032;        // float [512][2048]
static const size_t NOFF_XFW   = 50446336;        // float [64][8192]
static const size_t NOFF_BIAS  = 52543488;        // float [8192]
static const size_t NOFF_LPT   = 52576256;        // double [512][400]
static const size_t NOFF_GMAT  = 54214656;        // double [512][400]
static const size_t NOFF_INTS  = 55853056;        // int [1024]
static const size_t NOFF_A16E  = 55857152;        // half8 [4][4][1024]   (emb)
static const size_t NOFF_A16X  = 56119296;        // half8 [12][4][64][1024] (xf3)
static const size_t NOFF_A16F  = 106450944;       // half8 [4][64][1024]  (h2)
static const size_t NOFF_A16D  = 110645248;       // half8 [4][64][1024]  (hd)
static const size_t NOFF_B16G  = 114839552;       // half8 [64][132][1024] (Wih|Whh)
static const size_t NOFF_B16F  = 253251584;       // half8 [16][64][1024] (Wfc1)
static const size_t NOFF_B16O  = 270028800;       // half8 [4][64][1024]  (Wout)
static const size_t NWS_TOTAL  = 274223104;       // ~262 MB

#define SI_G    0
#define SI_LOGP 512
#define SI_SAMP 1024
#define SI_OUTS 7168
#define SI_ENT  13312
#define SI_WPQ  13376
#define SI_LGP  13824

using half8  = __attribute__((ext_vector_type(8))) _Float16;
using floatx4 = __attribute__((ext_vector_type(4))) float;

__device__ __forceinline__ void gload16(const void* g, void* l) {
    __builtin_amdgcn_global_load_lds((__attribute__((address_space(1))) void*)g,
                                     (__attribute__((address_space(3))) void*)l,
                                     16, 0, 0);
}

// split x into f16 hi + f16 lo' (lo' = 2048*(x - hi)), writing lane j of the
// half8 vectors (vectors passed by reference: vector-element references are
// not bindable, so subscripting must happen inside).
__device__ __forceinline__ void split16v(float x, half8& hi, half8& lo, int j) {
    _Float16 h = (_Float16)x;
    hi[j] = h;
    lo[j] = (_Float16)((x - (float)h) * 2048.0f);
}

// ---------------------------------------------------------------------------
// NEW: pre-tiled GEMM. C[z][512][N] partials = A[512,K]*B[N,K]^T.
// A/B are pre-split f16 hi/lo planes in fragment order; staging is pure
// global_load_lds (16B) into linear LDS; ds_read_b128 fragments conflict-free.
// Block 256 thr = 4 waves; tile 128x128; wave tile 64x64 = 4x4 of 16x16x32.
// A: up to 3 pre-tiled segments with chunk boundaries cA1/cA2 (absolute) and
// per-m_blk chunk strides chA*.  z = acc1 + acc2/2048 (identical math to old).
// ---------------------------------------------------------------------------
__global__ __launch_bounds__(256, 2)
void ij_gemm_pk(const half8* __restrict__ A0, const half8* __restrict__ A1,
                const half8* __restrict__ A2, int cA1, int cA2,
                int chA0, int chA1, int chA2,
                const half8* __restrict__ Bt, int totB,
                float* __restrict__ C, int N, int cpz)
{
    __shared__ half8 lds[2048];   // 32 KB: A hi|lo (1024), B hi|lo (1024)

    const int tid  = threadIdx.x;
    const int lane = tid & 63;
    const int wid  = tid >> 6;
    const int n0   = blockIdx.x * 128;
    const int m0   = blockIdx.y * 128;
    const int c0   = blockIdx.z * cpz;
    float* Cout = C + (size_t)blockIdx.z * ((size_t)512 * (size_t)N);

    const int wave_m = wid & 1;
    const int wave_n = wid >> 1;
    const int lo16 = lane & 15;
    const int oq   = lane >> 4;

    floatx4 acc1[4][4], acc2[4][4];
#pragma unroll
    for (int i = 0; i < 4; ++i)
#pragma unroll
        for (int j = 0; j < 4; ++j) { acc1[i][j] = (floatx4)0.f; acc2[i][j] = (floatx4)0.f; }

    for (int c = 0; c < cpz; ++c) {
        const int ca = c0 + c;
        __syncthreads();                       // prior chunk's ds_reads done
        if (wid < 2) {                         // waves 0,1 stage A (16 KB)
            const half8* ap; int cl, st;
            if (ca < cA1)      { ap = A0; cl = ca;       st = chA0; }
            else if (ca < cA2) { ap = A1; cl = ca - cA1; st = chA1; }
            else               { ap = A2; cl = ca - cA2; st = chA2; }
            const half8* src = ap + ((size_t)blockIdx.y * st + cl) * 1024 + lane;
#pragma unroll
            for (int j = 0; j < 8; ++j) {
                const int un = (wid * 8 + j) * 64;
                gload16(src + un, &lds[un]);
            }
        } else {                               // waves 2,3 stage B (16 KB)
            const half8* src = Bt + ((size_t)blockIdx.x * totB + ca) * 1024 + lane;
#pragma unroll
            for (int j = 0; j < 8; ++j) {
                const int un = ((wid - 2) * 8 + j) * 64;
                gload16(src + un, &lds[1024 + un]);
            }
        }
        __syncthreads();                       // drains vmcnt -> LDS ready

        half8 Ahi[4], Alo[4];
#pragma unroll
        for (int mt = 0; mt < 4; ++mt) {
            const int amt = wave_m * 4 + mt;
            Ahi[mt] = lds[amt * 64 + lane];
            Alo[mt] = lds[512 + amt * 64 + lane];
        }
#pragma unroll
        for (int nt = 0; nt < 4; ++nt) {
            const int bnt = wave_n * 4 + nt;
            half8 Bhi = lds[1024 + bnt * 64 + lane];
            half8 Blo = lds[1536 + bnt * 64 + lane];
#pragma unroll
            for (int mt = 0; mt < 4; ++mt) {
                acc1[mt][nt] = __builtin_amdgcn_mfma_f32_16x16x32_f16(Ahi[mt], Bhi, acc1[mt][nt], 0, 0, 0);
                acc2[mt][nt] = __builtin_amdgcn_mfma_f32_16x16x32_f16(Ahi[mt], Blo, acc2[mt][nt], 0, 0, 0);
                acc2[mt][nt] = __builtin_amdgcn_mfma_f32_16x16x32_f16(Alo[mt], Bhi, acc2[mt][nt], 0, 0, 0);
            }
        }
    }

    const float s = 1.0f / 2048.0f;
#pragma unroll
    for (int mt = 0; mt < 4; ++mt) {
        const int rbase = m0 + wave_m * 64 + mt * 16 + oq * 4;
#pragma unroll
        for (int nt = 0; nt < 4; ++nt) {
            const int col = n0 + wave_n * 64 + nt * 16 + lo16;
            if (col >= N) continue;
#pragma unroll
            for (int v = 0; v < 4; ++v) {
                float val = acc1[mt][nt][v] + acc2[mt][nt][v] * s;
                Cout[(size_t)(rbase + v) * N + col] = val;
            }
        }
    }
}

// ---------------------------------------------------------------------------
// NEW: generic weight/activation pre-tiler. One thread per (row, k-octet):
// coalesced row-major float4 reads, scattered 16B plane writes.
// Source is up to 2 concatenated K-segments (both row-major, N-major layout).
// ---------------------------------------------------------------------------
__global__ void ij_pack_w(const float* __restrict__ S0, const float* __restrict__ S1,
                          int kS1, int ld0, int ld1,
                          int Nw, int tot_ch, int total, half8* __restrict__ out)
{
    int gid = blockIdx.x * 256 + threadIdx.x;
    if (gid >= total) return;
    const int kpr  = tot_ch * 4;             // k-octets per row
    const int koct = gid % kpr;
    const int row  = gid / kpr;
    const int c  = koct >> 2;
    const int oqq = koct & 3;
    const int k0 = koct * 8;
    const int nb = row >> 7, mt = (row >> 4) & 7, lo16 = row & 15;
    const int u  = mt * 64 + oqq * 16 + lo16;

    half8 hi8, lo8;
    if (row < Nw) {
        const float* sp; int ko, ld;
        if (k0 < kS1) { sp = S0; ko = k0;       ld = ld0; }
        else          { sp = S1; ko = k0 - kS1; ld = ld1; }
        const float4 a = *(const float4*)(sp + (size_t)row * ld + ko);
        const float4 b = *(const float4*)(sp + (size_t)row * ld + ko + 4);
        float x[8] = {a.x, a.y, a.z, a.w, b.x, b.y, b.z, b.w};
#pragma unroll
        for (int j = 0; j < 8; ++j) split16v(x[j], hi8, lo8, j);
    } else {
#pragma unroll
        for (int j = 0; j < 8; ++j) { hi8[j] = (_Float16)0.f; lo8[j] = (_Float16)0.f; }
    }
    const size_t base = ((size_t)nb * tot_ch + c) * 1024;
    out[base + u]       = hi8;
    out[base + 512 + u] = lo8;
}

// emb = relu(W_emb[:,pop] + b_emb), packed directly into A16E tiles.
__global__ void ij_pack_emb(const float* __restrict__ W_emb, const float* __restrict__ b_emb,
                            const int* __restrict__ pop_t, half8* __restrict__ out)
{
    int gid = blockIdx.x * 256 + threadIdx.x;
    if (gid >= BKR * 16) return;             // 512 rows x 16 k-octets
    const int koct = gid & 15;
    const int row  = gid >> 4;
    const int c  = koct >> 2;
    const int oqq = koct & 3;
    const int k0 = koct * 8;
    const int nb = row >> 7, mt = (row >> 4) & 7, lo16 = row & 15;
    const int u  = mt * 64 + oqq * 16 + lo16;
    const int p  = pop_t[row];

    half8 hi8, lo8;
#pragma unroll
    for (int e = 0; e < 8; ++e) {
        const int col = k0 + e;
        float v = W_emb[col * DD + p] + b_emb[col];
        v = v > 0.f ? v : 0.f;
        split16v(v, hi8, lo8, e);
    }
    const size_t base = ((size_t)nb * 4 + c) * 1024;
    out[base + u]       = hi8;
    out[base + 512 + u] = lo8;
}

// LSTM elementwise, 8 elems/thread; fuses gate split-K reduce + xfW + bias,
// writes h2/c2 f32 and packs h2 into A16F (fc1 A-operand).
__global__ void ij_lstm_pk(const float* __restrict__ z0, const float* __restrict__ z1,
                           const float* __restrict__ xfw, const float* __restrict__ bias,
                           const float* __restrict__ c,
                           float* __restrict__ h2, float* __restrict__ c2,
                           half8* __restrict__ a16f)
{
    int gid = blockIdx.x * 256 + threadIdx.x;
    if (gid >= BKR * 256) return;
    const int r   = gid >> 8;
    const int oct = gid & 255;
    const int hh0 = oct * 8;
    const size_t zb = (size_t)r * G4;
    const float* xw = xfw + (size_t)(r & 63) * G4;

    float zg[4][8];
#pragma unroll
    for (int g = 0; g < 4; ++g) {
        const int base = g * HH + hh0;
        const float4 a0 = *(const float4*)(z0 + zb + base);
        const float4 a1 = *(const float4*)(z0 + zb + base + 4);
        const float4 b0 = *(const float4*)(z1 + zb + base);
        const float4 b1 = *(const float4*)(z1 + zb + base + 4);
        const float4 w0 = *(const float4*)(xw + base);
        const float4 w1 = *(const float4*)(xw + base + 4);
        const float4 s0 = *(const float4*)(bias + base);
        const float4 s1 = *(const float4*)(bias + base + 4);
        zg[g][0] = a0.x + b0.x + w0.x + s0.x;  zg[g][1] = a0.y + b0.y + w0.y + s0.y;
        zg[g][2] = a0.z + b0.z + w0.z + s0.z;  zg[g][3] = a0.w + b0.w + w0.w + s0.w;
        zg[g][4] = a1.x + b1.x + w1.x + s1.x;  zg[g][5] = a1.y + b1.y + w1.y + s1.y;
        zg[g][6] = a1.z + b1.z + w1.z + s1.z;  zg[g][7] = a1.w + b1.w + w1.w + s1.w;
    }
    const size_t ib = (size_t)r * HH + hh0;
    const float4 cp0 = *(const float4*)(c + ib);
    const float4 cp1 = *(const float4*)(c + ib + 4);
    float cprev[8] = {cp0.x, cp0.y, cp0.z, cp0.w, cp1.x, cp1.y, cp1.z, cp1.w};

    float h2v[8], c2v[8];
#pragma unroll
    for (int e = 0; e < 8; ++e) {
        float si = 1.f / (1.f + expf(-zg[0][e]));
        float sf = 1.f / (1.f + expf(-zg[1][e]));
        float gt = tanhf(zg[2][e]);
        float so = 1.f / (1.f + expf(-zg[3][e]));
        float cv = sf * cprev[e] + si * gt;
        c2v[e] = cv;
        h2v[e] = so * tanhf(cv);
    }
    *(float4*)(c2 + ib)     = make_float4(c2v[0], c2v[1], c2v[2], c2v[3]);
    *(float4*)(c2 + ib + 4) = make_float4(c2v[4], c2v[5], c2v[6], c2v[7]);
    *(float4*)(h2 + ib)     = make_float4(h2v[0], h2v[1], h2v[2], h2v[3]);
    *(float4*)(h2 + ib + 4) = make_float4(h2v[4], h2v[5], h2v[6], h2v[7]);

    half8 hi8, lo8;
#pragma unroll
    for (int e = 0; e < 8; ++e) split16v(h2v[e], hi8, lo8, e);
    const int cch = oct >> 2, oqq = oct & 3;
    const int mt = (r >> 4) & 7, lo16 = r & 15;
    const size_t base = ((size_t)(r >> 7) * 64 + cch) * 1024;
    const int u = mt * 64 + oqq * 16 + lo16;
    a16f[base + u]       = hi8;
    a16f[base + 512 + u] = lo8;
}

// fc1 reduce (8 split-K partials) + bias + relu, packed into A16D.
__global__ void ij_reduce_fc1_pk(const float* __restrict__ part, const float* __restrict__ b_fc1,
                                 half8* __restrict__ a16d)
{
    int gid = blockIdx.x * 256 + threadIdx.x;
    if (gid >= BKR * 256) return;
    const int r   = gid >> 8;
    const int oct = gid & 255;
    const int hh0 = oct * 8;
    const size_t i = (size_t)r * HH + hh0;

    float v[8];
    {
        const float4 b0 = *(const float4*)(b_fc1 + hh0);
        const float4 b1 = *(const float4*)(b_fc1 + hh0 + 4);
        v[0]=b0.x; v[1]=b0.y; v[2]=b0.z; v[3]=b0.w; v[4]=b1.x; v[5]=b1.y; v[6]=b1.z; v[7]=b1.w;
    }
#pragma unroll
    for (int s = 0; s < 8; ++s) {
        const float4 p0 = *(const float4*)(part + (size_t)s * 1048576 + i);
        const float4 p1 = *(const float4*)(part + (size_t)s * 1048576 + i + 4);
        v[0]+=p0.x; v[1]+=p0.y; v[2]+=p0.z; v[3]+=p0.w; v[4]+=p1.x; v[5]+=p1.y; v[6]+=p1.z; v[7]+=p1.w;
    }
    half8 hi8, lo8;
#pragma unroll
    for (int e = 0; e < 8; ++e) {
        float x = v[e] > 0.f ? v[e] : 0.f;
        split16v(x, hi8, lo8, e);
    }
    const int cch = oct >> 2, oqq = oct & 3;
    const int mt = (r >> 4) & 7, lo16 = r & 15;
    const size_t base = ((size_t)(r >> 7) * 64 + cch) * 1024;
    const int u = mt * 64 + oqq * 16 + lo16;
    a16d[base + u]       = hi8;
    a16d[base + 512 + u] = lo8;
}

// beam-order permute: c <- c2[order], and h2[order] packed into A16H.
__global__ void ij_permute_pk(const float* __restrict__ h2, const float* __restrict__ c2,
                              const int* __restrict__ order_g,
                              float* __restrict__ c, half8* __restrict__ a16h)
{
    int gid = blockIdx.x * 256 + threadIdx.x;
    if (gid >= BKR * 256) return;
    const int r   = gid >> 8;
    const int oct = gid & 255;
    const int hh0 = oct * 8;
    const int o   = order_g[r];
    const size_t so_ = (size_t)o * HH + hh0;
    const size_t di  = (size_t)r * HH + hh0;

    const float4 cc0 = *(const float4*)(c2 + so_);
    const float4 cc1 = *(const float4*)(c2 + so_ + 4);
    *(float4*)(c + di)     = cc0;
    *(float4*)(c + di + 4) = cc1;

    const float4 hh0v = *(const float4*)(h2 + so_);
    const float4 hh1v = *(const float4*)(h2 + so_ + 4);
    float hv[8] = {hh0v.x, hh0v.y, hh0v.z, hh0v.w, hh1v.x, hh1v.y, hh1v.z, hh1v.w};
    half8 hi8, lo8;
#pragma unroll
    for (int e = 0; e < 8; ++e) split16v(hv[e], hi8, lo8, e);
    const int cch = oct >> 2, oqq = oct & 3;
    const int mt = (r >> 4) & 7, lo16 = r & 15;
    const size_t base = ((size_t)(r >> 7) * 64 + cch) * 1024;
    const int u = mt * 64 + oqq * 16 + lo16;
    a16h[base + u]       = hi8;
    a16h[base + 512 + u] = lo8;
}

// ---------------------------------------------------------------------------
// OLD (fallback) f16-split reg-staging GEMM — verified round-3 kernel.
// ---------------------------------------------------------------------------
__global__ __launch_bounds__(256, 2)
void ij_gemm_f16x3(const float* __restrict__ A0, const float* __restrict__ A1,
                   const float* __restrict__ A2, int kA1, int kA2,
                   int lda0, int lda1, int lda2,
                   const float* __restrict__ B0, const float* __restrict__ B1,
                   int kB1, int ldb0, int ldb1,
                   float* __restrict__ C, int N, int Klen)
{
    __shared__ half8 lds[2048];

    const int tid = threadIdx.x;
    const int n0  = blockIdx.x * 128;
    const int m0  = blockIdx.y * 128;
    const int kstart = blockIdx.z * Klen;
    const int nch = Klen / 32;
    float* Cout = C + (size_t)blockIdx.z * ((size_t)512 * (size_t)N);

    const int wid    = tid >> 6;
    const int wave_m = wid & 1;
    const int wave_n = wid >> 1;
    const int lane   = tid & 63;
    const int lo16   = lane & 15;
    const int oq     = lane >> 4;
    const int laneSlot = oq * 16 + ((lo16 + 4 * oq) & 15);

    const int st_o   = tid & 3;
    const int st_row0 = tid >> 2;

    float4 pfA[2][2], pfB[2][2];

    auto loadGlobals = [&](int c) {
        const int kb = kstart + c * 32;
#pragma unroll
        for (int i = 0; i < 2; ++i) {
            const int row = st_row0 + i * 64;
            const int kc  = kb + st_o * 8;
            const float* ap; int ao, ld;
            if (kc < kA1)      { ap = A0; ao = kc;       ld = lda0; }
            else if (kc < kA2) { ap = A1; ao = kc - kA1; ld = lda1; }
            else               { ap = A2; ao = kc - kA2; ld = lda2; }
            const float* p = ap + (size_t)(m0 + row) * ld + ao;
            pfA[i][0] = *(const float4*)(p);
            pfA[i][1] = *(const float4*)(p + 4);
            const int bn = n0 + row;
            const float* bp; int bo, bld;
            if (kc < kB1) { bp = B0; bo = kc;       bld = ldb0; }
            else          { bp = B1; bo = kc - kB1; bld = ldb1; }
            if (bn < N) {
                const float* q = bp + (size_t)bn * bld + bo;
                pfB[i][0] = *(const float4*)(q);
                pfB[i][1] = *(const float4*)(q + 4);
            } else {
                pfB[i][0] = make_float4(0.f,0.f,0.f,0.f);
                pfB[i][1] = make_float4(0.f,0.f,0.f,0.f);
            }
        }
    };

    auto writeLDS = [&]() {
#pragma unroll
        for (int i = 0; i < 2; ++i) {
            const int row = st_row0 + i * 64;
            const int mt  = row >> 4;
            const int idx = mt * 64 + st_o * 16 + (((row & 15) + 4 * st_o) & 15);
            {
                float x[8] = {pfA[i][0].x, pfA[i][0].y, pfA[i][0].z, pfA[i][0].w,
                              pfA[i][1].x, pfA[i][1].y, pfA[i][1].z, pfA[i][1].w};
                half8 hi8, lo8;
#pragma unroll
                for (int j = 0; j < 8; ++j) split16v(x[j], hi8, lo8, j);
                lds[idx]       = hi8;
                lds[512 + idx] = lo8;
            }
            {
                float x[8] = {pfB[i][0].x, pfB[i][0].y, pfB[i][0].z, pfB[i][0].w,
                              pfB[i][1].x, pfB[i][1].y, pfB[i][1].z, pfB[i][1].w};
                half8 hi8, lo8;
#pragma unroll
                for (int j = 0; j < 8; ++j) split16v(x[j], hi8, lo8, j);
                lds[1024 + idx] = hi8;
                lds[1536 + idx] = lo8;
            }
        }
    };

    floatx4 acc1[4][4], acc2[4][4];
#pragma unroll
    for (int i = 0; i < 4; ++i)
#pragma unroll
        for (int j = 0; j < 4; ++j) { acc1[i][j] = (floatx4)0.f; acc2[i][j] = (floatx4)0.f; }

    loadGlobals(0);
    for (int c = 0; c < nch; ++c) {
        __syncthreads();
        writeLDS();
        __syncthreads();
        if (c + 1 < nch) loadGlobals(c + 1);

        half8 Ahi[4], Alo[4];
#pragma unroll
        for (int mt = 0; mt < 4; ++mt) {
            const int amt = wave_m * 4 + mt;
            Ahi[mt] = lds[amt * 64 + laneSlot];
            Alo[mt] = lds[512 + amt * 64 + laneSlot];
        }
#pragma unroll
        for (int nt = 0; nt < 4; ++nt) {
            const int bnt = wave_n * 4 + nt;
            half8 Bhi = lds[1024 + bnt * 64 + laneSlot];
            half8 Blo = lds[1536 + bnt * 64 + laneSlot];
#pragma unroll
            for (int mt = 0; mt < 4; ++mt) {
                acc1[mt][nt] = __builtin_amdgcn_mfma_f32_16x16x32_f16(Ahi[mt], Bhi, acc1[mt][nt], 0, 0, 0);
                acc2[mt][nt] = __builtin_amdgcn_mfma_f32_16x16x32_f16(Ahi[mt], Blo, acc2[mt][nt], 0, 0, 0);
                acc2[mt][nt] = __builtin_amdgcn_mfma_f32_16x16x32_f16(Alo[mt], Bhi, acc2[mt][nt], 0, 0, 0);
            }
        }
    }

    const float s = 1.0f / 2048.0f;
#pragma unroll
    for (int mt = 0; mt < 4; ++mt) {
        const int rbase = m0 + wave_m * 64 + mt * 16 + oq * 4;
#pragma unroll
        for (int nt = 0; nt < 4; ++nt) {
            const int col = n0 + wave_n * 64 + nt * 16 + lo16;
            if (col >= N) continue;
#pragma unroll
            for (int v = 0; v < 4; ++v) {
                float val = acc1[mt][nt][v] + acc2[mt][nt][v] * s;
                Cout[(size_t)(rbase + v) * N + col] = val;
            }
        }
    }
}

// ---------------------------------------------------------------------------
// fp32 vector GEMM (one-time xfW precompute, M=64).
// ---------------------------------------------------------------------------
#define FBM 128
#define FBN 64
#define FBK 16

__global__ __launch_bounds__(256, 2)
void ij_gemm_f32(const float* __restrict__ A0, const float* __restrict__ A1,
                 const float* __restrict__ A2, int kA1, int kA2,
                 int lda0, int lda1, int lda2,
                 const float* __restrict__ B0, const float* __restrict__ B1,
                 int kB1, int ldb0, int ldb1,
                 float* __restrict__ C, int M, int N, int Klen)
{
    __shared__ float As[2][FBK][FBM];
    __shared__ float Bs[2][FBK][FBN];

    const int tid = threadIdx.x;
    const int tx  = tid & 15;
    const int ty  = tid >> 4;
    const int n0  = blockIdx.x * FBN;
    const int m0  = blockIdx.y * FBM;
    const int kstart = blockIdx.z * Klen;
    const int nch = Klen / FBK;
    float* Cout = C + (size_t)blockIdx.z * ((size_t)M * (size_t)N);

    const int srow = tid >> 2;
    const int kq   = tid & 3;

    float4 aR0, aR1, bR;

    auto loadChunk = [&](int kb0) {
        const int kc = kb0 + kq * 4;
        const float* ap; int ao, ld;
        if (kc < kA1)      { ap = A0; ao = kc;       ld = lda0; }
        else if (kc < kA2) { ap = A1; ao = kc - kA1; ld = lda1; }
        else               { ap = A2; ao = kc - kA2; ld = lda2; }
        const int r0 = m0 + srow, r1 = r0 + 64;
        aR0 = (r0 < M) ? *(const float4*)(ap + (size_t)r0 * ld + ao)
                       : make_float4(0.f, 0.f, 0.f, 0.f);
        aR1 = (r1 < M) ? *(const float4*)(ap + (size_t)r1 * ld + ao)
                       : make_float4(0.f, 0.f, 0.f, 0.f);
        const float* bp; int bo, bld;
        if (kc < kB1) { bp = B0; bo = kc;       bld = ldb0; }
        else          { bp = B1; bo = kc - kB1; bld = ldb1; }
        const int bn = n0 + srow;
        bR = (bn < N) ? *(const float4*)(bp + (size_t)bn * bld + bo)
                      : make_float4(0.f, 0.f, 0.f, 0.f);
    };
    auto storeChunk = [&](int bsel) {
        const int k4 = kq * 4;
        As[bsel][k4+0][srow]      = aR0.x;
        As[bsel][k4+1][srow]      = aR0.y;
        As[bsel][k4+2][srow]      = aR0.z;
        As[bsel][k4+3][srow]      = aR0.w;
        As[bsel][k4+0][srow + 64] = aR1.x;
        As[bsel][k4+1][srow + 64] = aR1.y;
        As[bsel][k4+2][srow + 64] = aR1.z;
        As[bsel][k4+3][srow + 64] = aR1.w;
        Bs[bsel][k4+0][srow]      = bR.x;
        Bs[bsel][k4+1][srow]      = bR.y;
        Bs[bsel][k4+2][srow]      = bR.z;
        Bs[bsel][k4+3][srow]      = bR.w;
    };

    float acc[8][4];
#pragma unroll
    for (int i = 0; i < 8; ++i)
#pragma unroll
        for (int j = 0; j < 4; ++j) acc[i][j] = 0.f;

    loadChunk(kstart);
    storeChunk(0);
    __syncthreads();
    int bsel = 0;
    for (int c = 0; c < nch; ++c) {
        if (c + 1 < nch) loadChunk(kstart + (c + 1) * FBK);
#pragma unroll
        for (int kkk = 0; kkk < FBK; ++kkk) {
            float a[8], b[4];
            const float4 av0 = *(const float4*)&As[bsel][kkk][ty * 8];
            const float4 av1 = *(const float4*)&As[bsel][kkk][ty * 8 + 4];
            a[0]=av0.x; a[1]=av0.y; a[2]=av0.z; a[3]=av0.w;
            a[4]=av1.x; a[5]=av1.y; a[6]=av1.z; a[7]=av1.w;
            const float2 bv0 = *(const float2*)&Bs[bsel][kkk][tx * 2];
            const float2 bv1 = *(const float2*)&Bs[bsel][kkk][tx * 2 + 32];
            b[0]=bv0.x; b[1]=bv0.y; b[2]=bv1.x; b[3]=bv1.y;
#pragma unroll
            for (int i = 0; i < 8; ++i)
#pragma unroll
                for (int j = 0; j < 4; ++j)
                    acc[i][j] = fmaf(a[i], b[j], acc[i][j]);
        }
        if (c + 1 < nch) storeChunk(bsel ^ 1);
        __syncthreads();
        bsel ^= 1;
    }

#pragma unroll
    for (int i = 0; i < 8; ++i) {
        const int row = m0 + ty * 8 + i;
        if (row >= M) continue;
        const size_t rbase = (size_t)row * N;
#pragma unroll
        for (int g = 0; g < 2; ++g) {
            const int col = n0 + tx * 2 + g * 32;
            if (col + 1 < N) {
                float2 st; st.x = acc[i][g*2+0]; st.y = acc[i][g*2+1];
                *(float2*)(Cout + rbase + col) = st;
            } else if (col < N) {
                Cout[rbase + col] = acc[i][g*2+0];
            }
        }
    }
}

// ---------------------------------------------------------------------------
__global__ void ij_bias_kernel(const float* __restrict__ b_ih, const float* __restrict__ b_hh,
                               float* __restrict__ bias)
{
    int i = blockIdx.x * 256 + threadIdx.x;
    if (i < G4) bias[i] = b_ih[i] + b_hh[i];
}

__global__ void ij_emb_kernel(const float* __restrict__ W_emb, const float* __restrict__ b_emb,
                              const int* __restrict__ pop_t, float* __restrict__ emb)
{
    int i = blockIdx.x * 256 + threadIdx.x;
    if (i >= BKR * EE) return;
    int r = i >> 7, e = i & 127;
    float v = W_emb[e * DD + pop_t[r]] + b_emb[e];
    emb[i] = v > 0.f ? v : 0.f;
}

// OLD fallback LSTM elementwise (split-K=2 reduce + xfW + bias).
__global__ void ij_lstm_kernel(const float* __restrict__ z0, const float* __restrict__ z1,
                               const float* __restrict__ xfw, const float* __restrict__ bias,
                               const float* __restrict__ c,
                               float* __restrict__ h2, float* __restrict__ c2)
{
    int i = blockIdx.x * 256 + threadIdx.x;
    if (i >= BKR * HH) return;
    int r = i >> 11, hh = i & 2047;
    const size_t zb = (size_t)r * G4;
    const float* xw = xfw + (size_t)(r & 63) * G4;
    float iv = z0[zb + hh]        + z1[zb + hh]        + xw[hh]        + bias[hh];
    float fv = z0[zb + HH + hh]   + z1[zb + HH + hh]   + xw[HH + hh]   + bias[HH + hh];
    float gv = z0[zb + 2*HH + hh] + z1[zb + 2*HH + hh] + xw[2*HH + hh] + bias[2*HH + hh];
    float ov = z0[zb + 3*HH + hh] + z1[zb + 3*HH + hh] + xw[3*HH + hh] + bias[3*HH + hh];
    float si = 1.f / (1.f + expf(-iv));
    float sf = 1.f / (1.f + expf(-fv));
    float so = 1.f / (1.f + expf(-ov));
    float cv = sf * c[i] + si * tanhf(gv);
    c2[i] = cv;
    h2[i] = so * tanhf(cv);
}

__global__ void ij_reduce_fc1_kernel(const float* __restrict__ part, const float* __restrict__ b_fc1,
                                     float* __restrict__ hd)
{
    int i = blockIdx.x * 256 + threadIdx.x;
    if (i >= BKR * HH) return;
    float v = part[i] + part[i + 1048576] + part[i + 2097152] + part[i + 3145728]
            + b_fc1[i & 2047];
    hd[i] = v > 0.f ? v : 0.f;
}

__global__ void ij_reduce_xfw_kernel(const float* __restrict__ part, float* __restrict__ xfw)
{
    int i = blockIdx.x * 256 + threadIdx.x;
    if (i >= BB * G4) return;
    xfw[i] = part[i] + part[i + 524288] + part[i + 1048576] + part[i + 1572864];
}

// ---------------------------------------------------------------------------
// Per-row: reduce 16 logits partials + b_out + mask row, log_softmax, greedy
// argmax, Gumbel-with-max conditioned g. All f64 (decision-critical).
// ---------------------------------------------------------------------------
__global__ __launch_bounds__(256)
void ij_softmax_g_kernel(const float* __restrict__ part, const float* __restrict__ b_out,
                         const float* __restrict__ mask_table, const int* __restrict__ pop_t,
                         const float* __restrict__ gum_t, const double* __restrict__ G,
                         const double* __restrict__ logp,
                         double* __restrict__ logp_tok, double* __restrict__ gmat,
                         int* __restrict__ greedy)
{
    const int r = blockIdx.x, tid = threadIdx.x;
    __shared__ double sred[256];
    __shared__ int    sidx[256];
    __shared__ double sbc[2];

    const int pop = pop_t[r];
    const int j0 = tid, j1 = tid + 256;
    double lg0 = -INFINITY, lg1 = -INFINITY;
    if (j0 < DD) {
        double v = (double)b_out[j0] + (double)mask_table[pop * DD + j0];
#pragma unroll
        for (int s = 0; s < 16; ++s) v += (double)part[(size_t)s * (BKR*DD) + (size_t)r * DD + j0];
        lg0 = v;
    }
    if (j1 < DD) {
        double v = (double)b_out[j1] + (double)mask_table[pop * DD + j1];
#pragma unroll
        for (int s = 0; s < 16; ++s) v += (double)part[(size_t)s * (BKR*DD) + (size_t)r * DD + j1];
        lg1 = v;
    }
    double mv = lg0; int mi = j0;
    if (lg1 > mv) { mv = lg1; mi = j1; }
    sred[tid] = mv; sidx[tid] = mi;
    __syncthreads();
    for (int off = 128; off > 0; off >>= 1) {
        if (tid < off) {
            double ov = sred[tid+off]; int oi = sidx[tid+off];
            if (ov > sred[tid] || (ov == sred[tid] && oi < sidx[tid])) { sred[tid] = ov; sidx[tid] = oi; }
        }
        __syncthreads();
    }
    if (tid == 0) { sbc[0] = sred[0]; greedy[r] = sidx[0]; }
    __syncthreads();
    const double rowmax = sbc[0];

    double es = 0.0;
    if (j0 < DD) es += exp(lg0 - rowmax);
    if (j1 < DD) es += exp(lg1 - rowmax);
    __syncthreads();
    sred[tid] = es;
    __syncthreads();
    for (int off = 128; off > 0; off >>= 1) {
        if (tid < off) sred[tid] += sred[tid+off];
        __syncthreads();
    }
    if (tid == 0) sbc[1] = log(sred[0]);
    __syncthreads();
    const double lse = sbc[1];
    const double lpr = logp[r], Gr = G[r];

    double gp0 = -INFINITY, gp1 = -INFINITY;
    if (j0 < DD) {
        double lt = lg0 - rowmax - lse;
        logp_tok[(size_t)r * DD + j0] = lt;
        double u = (double)gum_t[(size_t)r * DD + j0];
        u = fmin(fmax(u, 1e-9), 1.0 - 1e-9);
        gp0 = lt + lpr + (-log(-log(u)));
    }
    if (j1 < DD) {
        double lt = lg1 - rowmax - lse;
        logp_tok[(size_t)r * DD + j1] = lt;
        double u = (double)gum_t[(size_t)r * DD + j1];
        u = fmin(fmax(u, 1e-9), 1.0 - 1e-9);
        gp1 = lt + lpr + (-log(-log(u)));
    }
    __syncthreads();
    sred[tid] = fmax(gp0, gp1);
    __syncthreads();
    for (int off = 128; off > 0; off >>= 1) {
        if (tid < off) sred[tid] = fmax(sred[tid], sred[tid+off]);
        __syncthreads();
    }
    const double Z = sred[0];
    if (j0 < DD) {
        double v = Gr - gp0 + log1p(-exp(gp0 - Z));
        gmat[(size_t)r * DD + j0] = Gr - fmax(v, 0.0) - log1p(exp(-fabs(v)));
    }
    if (j1 < DD) {
        double v = Gr - gp1 + log1p(-exp(gp1 - Z));
        gmat[(size_t)r * DD + j1] = Gr - fmax(v, 0.0) - log1p(exp(-fabs(v)));
    }
}

// ---------------------------------------------------------------------------
// One block per image b: top-8 of 3200 (desc, low index on tie), bookkeeping.
// ---------------------------------------------------------------------------
__global__ __launch_bounds__(256)
void ij_beam_kernel(const double* __restrict__ gmat, const double* __restrict__ logp_tok,
                    const int* __restrict__ greedy, const int* __restrict__ pop_t,
                    const float* __restrict__ mask_table,
                    double* __restrict__ G, double* __restrict__ logp,
                    double* __restrict__ samples, double* __restrict__ outs,
                    double* __restrict__ entacc, double* __restrict__ wpq,
                    double* __restrict__ lgp_o, int* __restrict__ order_g, int t)
{
    const int b = blockIdx.x, tid = threadIdx.x;
    __shared__ double sv[256];
    __shared__ int    si2[256];
    __shared__ double gval8[8];
    __shared__ int    gidx8[8];
    __shared__ int    ord8[8], smp8[8];
    __shared__ double lp28[8], sel8[8], Gn8[8];
    __shared__ double oldS[8][TT], oldO[8][TT];
    __shared__ double efull[8];

    if (t > 0) {
        for (int pass = 0; pass < 8; ++pass) {
            double bv = -INFINITY; int bi = 0x7fffffff;
            for (int cand = tid; cand < KK * DD; cand += 256) {
                bool used = false;
                for (int p = 0; p < pass; ++p) used |= (gidx8[p] == cand);
                if (used) continue;
                int kb2 = cand / DD, d = cand - kb2 * DD;
                double v = gmat[(size_t)(kb2 * BB + b) * DD + d];
                if (v > bv || (v == bv && cand < bi)) { bv = v; bi = cand; }
            }
            sv[tid] = bv; si2[tid] = bi;
            __syncthreads();
            for (int off = 128; off > 0; off >>= 1) {
                if (tid < off) {
                    double ov = sv[tid+off]; int oi = si2[tid+off];
                    if (ov > sv[tid] || (ov == sv[tid] && oi < si2[tid])) { sv[tid] = ov; si2[tid] = oi; }
                }
                __syncthreads();
            }
            if (tid == 0) { gval8[pass] = sv[0]; gidx8[pass] = si2[0]; }
            __syncthreads();
        }
    }

    if (tid < 8) {
        const int s = tid, rp = s * BB + b;
        int ord, smp; double Gn;
        if (t == 0) { ord = rp; smp = greedy[rp]; Gn = G[rp]; }
        else {
            int idx = gidx8[s]; int kb2 = idx / DD;
            ord = kb2 * BB + b; smp = idx - kb2 * DD; Gn = gval8[s];
        }
        ord8[s] = ord; smp8[s] = smp; Gn8[s] = Gn;
        double sel = logp_tok[(size_t)ord * DD + smp];
        double lp2 = (t == 0) ? logp[ord] : logp[ord] + sel;
        sel8[s] = sel; lp28[s] = lp2;
    }
    __syncthreads();
    if (tid < 8 * TT) {
        int s = tid / TT, ttc = tid - s * TT;
        oldS[s][ttc] = samples[ord8[s] * TT + ttc];
        oldO[s][ttc] = outs[ord8[s] * TT + ttc];
    }
    __syncthreads();
    if (tid < 8 * TT) {
        int s = tid / TT, ttc = tid - s * TT;
        int rp = s * BB + b;
        samples[rp * TT + ttc] = (ttc == t) ? (double)smp8[s] : oldS[s][ttc];
        outs[rp * TT + ttc]    = (ttc == t) ? sel8[s]         : oldO[s][ttc];
    }
    if (tid >= 96 && tid < 104) {
        int s = tid - 96, rp = s * BB + b;
        G[rp]       = Gn8[s];
        logp[rp]    = lp28[s];
        order_g[rp] = ord8[s];
    }

    if (t > 0) {
        for (int s = 0; s < KK - 1; ++s) {
            const int ord = ord8[s];
            const double* lrow = logp_tok + (size_t)ord * DD;
            const float*  mrow = mask_table + (size_t)pop_t[ord] * DD;
            double acc = 0.0;
            for (int j = tid; j < DD; j += 256) {
                double lp_ = lrow[j];
                if (mrow[j] == 0.0f) acc += lp_ * exp(lp_);
            }
            __syncthreads();
            sv[tid] = acc;
            __syncthreads();
            for (int off = 128; off > 0; off >>= 1) {
                if (tid < off) sv[tid] += sv[tid+off];
                __syncthreads();
            }
            if (tid == 0) efull[s] = sv[0];
            __syncthreads();
        }
        if (tid == 0) {
            const double gk = gval8[7];
            double sw = 0.0, swe = 0.0;
            for (int s = 0; s < KK - 1; ++s) {
                double phi = lp28[s];
                double x = gk - phi;
                double y = exp(-x);
                double gls;
                if (x >= 10.0) gls = -x - y * 0.5 + y * y * (1.0 / 24.0);
                else           gls = log(-expm1(-exp(-fmin(x, 10.0))));
                double w = exp(phi - gls);
                wpq[b * (KK-1) + s]   = w;
                lgp_o[b * (KK-1) + s] = phi;
                sw += w; swe += w * efull[s];
            }
            entacc[b] += swe / sw;
        }
    }
}

__global__ void ij_permute_kernel(const float* __restrict__ h2, const float* __restrict__ c2,
                                  const int* __restrict__ order_g,
                                  float* __restrict__ h, float* __restrict__ c)
{
    int i = blockIdx.x * 256 + threadIdx.x;
    if (i >= BKR * HH) return;
    int r = i >> 11, j = i & 2047;
    int o = order_g[r];
    h[i] = h2[(size_t)o * HH + j];
    c[i] = c2[(size_t)o * HH + j];
}

__global__ void ij_final_kernel(const double* __restrict__ outs, const double* __restrict__ samples,
                                const double* __restrict__ entacc, const double* __restrict__ wpq,
                                const double* __restrict__ lgp_o, float* __restrict__ out)
{
    int i = blockIdx.x * 256 + threadIdx.x;
    if (i < 5376) {
        int bb = i / 84, rest = i - bb * 84;
        int s = rest / TT, ttc = rest - s * TT;
        size_t src = (size_t)(s * BB + bb) * TT + ttc;
        out[i]        = (float)outs[src];
        out[5376 + i] = (float)samples[src];
    } else if (i < 5440) {
        out[10752 + (i - 5376)] = (float)entacc[i - 5376];
    } else if (i < 5888) {
        int q = i - 5440; out[10816 + q] = (float)wpq[q];
    } else if (i < 6336) {
        int q = i - 5888; out[11264 + q] = (float)lgp_o[q];
    }
}

// ---------------------------------------------------------------------------
extern "C" void kernel_launch(void* const* d_in, const int* in_sizes, int n_in,
                              void* d_out, int out_size, void* d_ws, size_t ws_size,
                              hipStream_t stream)
{
    const float* x_f   = (const float*)d_in[0];
    const float* x_f3  = (const float*)d_in[1];
    const float* gum   = (const float*)d_in[2];
    const int*   pop   = (const int*)d_in[3];
    const float* mask  = (const float*)d_in[4];
    const float* W_emb = (const float*)d_in[5];
    const float* b_emb = (const float*)d_in[6];
    const float* W_ih  = (const float*)d_in[7];
    const float* W_hh  = (const float*)d_in[8];
    const float* b_ih  = (const float*)d_in[9];
    const float* b_hh  = (const float*)d_in[10];
    const float* W_fc1 = (const float*)d_in[11];
    const float* b_fc1 = (const float*)d_in[12];
    const float* W_out = (const float*)d_in[13];
    const float* b_out = (const float*)d_in[14];
    float* out = (float*)d_out;
    char*  ws  = (char*)d_ws;

    if (ws_size >= NWS_TOTAL) {
        // ---------------- NEW pre-split path ----------------
        double* STATE = (double*)(ws + NOFF_STATE);
        double* Gv    = STATE + SI_G;
        double* LOGP  = STATE + SI_LOGP;
        double* SAMP  = STATE + SI_SAMP;
        double* OUTS  = STATE + SI_OUTS;
        double* ENT   = STATE + SI_ENT;
        double* WPQ   = STATE + SI_WPQ;
        double* LGP   = STATE + SI_LGP;
        float*  Cc    = (float*)(ws + NOFF_C);
        half8*  A16H  = (half8*)(ws + NOFF_A16H);
        float*  Z     = (float*)(ws + NOFF_Z);
        float*  Z1    = Z + (size_t)BKR * G4;
        float*  H2    = (float*)(ws + NOFF_H2);
        float*  C2    = (float*)(ws + NOFF_C2);
        float*  XFW   = (float*)(ws + NOFF_XFW);
        float*  BIAS  = (float*)(ws + NOFF_BIAS);
        double* LPT   = (double*)(ws + NOFF_LPT);
        double* GMAT  = (double*)(ws + NOFF_GMAT);
        int*    ORDER = (int*)(ws + NOFF_INTS);
        int*    GREEDY= ORDER + 512;
        half8*  A16E  = (half8*)(ws + NOFF_A16E);
        half8*  A16X  = (half8*)(ws + NOFF_A16X);
        half8*  A16F  = (half8*)(ws + NOFF_A16F);
        half8*  A16D  = (half8*)(ws + NOFF_A16D);
        half8*  B16G  = (half8*)(ws + NOFF_B16G);
        half8*  B16F  = (half8*)(ws + NOFF_B16F);
        half8*  B16O  = (half8*)(ws + NOFF_B16O);

        hipMemsetAsync(ws, 0, NZERO_END, stream);   // STATE + Cc + A16H(h=0)
        ij_bias_kernel<<<32, 256, 0, stream>>>(b_ih, b_hh, BIAS);

        // one-time weight pre-tiling into f16 hi/lo fragment planes
        {
            int tot = 8192 * 132 * 4;     // gate B: [Wih cols 2048..4224 | Whh]
            ij_pack_w<<<(tot + 255) / 256, 256, 0, stream>>>(
                W_ih + 2048, W_hh, 2176, 4224, 2048, 8192, 132, tot, B16G);
            tot = 2048 * 64 * 4;          // fc1 B
            ij_pack_w<<<(tot + 255) / 256, 256, 0, stream>>>(
                W_fc1, nullptr, 1 << 30, 2048, 0, 2048, 64, tot, B16F);
            tot = 512 * 64 * 4;           // logits B (rows 400..511 zero-pad)
            ij_pack_w<<<(tot + 255) / 256, 256, 0, stream>>>(
                W_out, nullptr, 1 << 30, 2048, 0, 400, 64, tot, B16O);
            tot = 512 * 64 * 4;           // xf3 slices, all 12 t
            for (int t = 0; t < TT; ++t)
                ij_pack_w<<<(tot + 255) / 256, 256, 0, stream>>>(
                    x_f3 + (size_t)t * BKR * 2048, nullptr, 1 << 30, 2048, 0,
                    512, 64, tot, A16X + (size_t)t * 262144);
        }

        // xfW = x_f @ W_ih[:, :2048]^T  (one-time fp32 vector GEMM, M=64)
        ij_gemm_f32<<<dim3(128, 1, 4), 256, 0, stream>>>(
            x_f, nullptr, nullptr, 1 << 30, 1 << 30, 2048, 0, 0,
            W_ih, nullptr, 1 << 30, 4224, 0,
            Z, BB, G4, 512);
        ij_reduce_xfw_kernel<<<2048, 256, 0, stream>>>(Z, XFW);

        for (int t = 0; t < TT; ++t) {
            const int* pop_t = pop + t * BKR;
            ij_pack_emb<<<32, 256, 0, stream>>>(W_emb, b_emb, pop_t, A16E);

            // gate GEMM: A=[emb(ch0..3)|xf3_t(ch4..67)|h(ch68..131)], B=B16G
            ij_gemm_pk<<<dim3(64, 4, 2), 256, 0, stream>>>(
                A16E, A16X + (size_t)t * 262144, A16H, 4, 68, 4, 64, 64,
                B16G, 132, Z, G4, 66);

            ij_lstm_pk<<<512, 256, 0, stream>>>(Z, Z1, XFW, BIAS, Cc, H2, C2, A16F);

            // fc1 (split-K=8)
            ij_gemm_pk<<<dim3(16, 4, 8), 256, 0, stream>>>(
                A16F, A16F, A16F, 1 << 30, 1 << 30, 64, 64, 64,
                B16F, 64, Z, HH, 8);
            ij_reduce_fc1_pk<<<512, 256, 0, stream>>>(Z, b_fc1, A16D);

            // logits (split-K=16; reduce folded into softmax kernel)
            ij_gemm_pk<<<dim3(4, 4, 16), 256, 0, stream>>>(
                A16D, A16D, A16D, 1 << 30, 1 << 30, 64, 64, 64,
                B16O, 64, Z, DD, 4);

            ij_softmax_g_kernel<<<512, 256, 0, stream>>>(
                Z, b_out, mask, pop_t, gum + (size_t)t * BKR * DD,
                Gv, LOGP, LPT, GMAT, GREEDY);

            ij_beam_kernel<<<64, 256, 0, stream>>>(
                GMAT, LPT, GREEDY, pop_t, mask,
                Gv, LOGP, SAMP, OUTS, ENT, WPQ, LGP, ORDER, t);

            ij_permute_pk<<<512, 256, 0, stream>>>(H2, C2, ORDER, Cc, A16H);
        }

        ij_final_kernel<<<25, 256, 0, stream>>>(OUTS, SAMP, ENT, WPQ, LGP, out);
        (void)in_sizes; (void)n_in; (void)out_size;
        return;
    }

    // ---------------- OLD fallback path (round-3 verified) ----------------
    if (ws_size < WS_TOTAL) return;

    double* STATE = (double*)(ws + OFF_STATE);
    double* Gv    = STATE + SI_G;
    double* LOGP  = STATE + SI_LOGP;
    double* SAMP  = STATE + SI_SAMP;
    double* OUTS  = STATE + SI_OUTS;
    double* ENT   = STATE + SI_ENT;
    double* WPQ   = STATE + SI_WPQ;
    double* LGP   = STATE + SI_LGP;
    float*  H     = (float*)(ws + OFF_H);
    float*  Cc    = (float*)(ws + OFF_C);
    float*  Z     = (float*)(ws + OFF_Z);
    float*  Z1    = Z + (size_t)BKR * G4;
    float*  H2    = (float*)(ws + OFF_H2);
    float*  C2    = (float*)(ws + OFF_C2);
    float*  HD    = (float*)(ws + OFF_HD);
    float*  EMB   = (float*)(ws + OFF_EMB);
    float*  XFW   = (float*)(ws + OFF_XFW);
    float*  BIAS  = (float*)(ws + OFF_BIAS);
    double* LPT   = (double*)(ws + OFF_LPT);
    double* GMAT  = (double*)(ws + OFF_GMAT);
    int*    ORDER = (int*)(ws + OFF_INTS);
    int*    GREEDY= ORDER + 512;

    hipMemsetAsync(ws, 0, ZERO_END, stream);
    ij_bias_kernel<<<32, 256, 0, stream>>>(b_ih, b_hh, BIAS);

    ij_gemm_f32<<<dim3(128, 1, 4), 256, 0, stream>>>(
        x_f, nullptr, nullptr, 1 << 30, 1 << 30, 2048, 0, 0,
        W_ih, nullptr, 1 << 30, 4224, 0,
        Z, BB, G4, 512);
    ij_reduce_xfw_kernel<<<2048, 256, 0, stream>>>(Z, XFW);

    for (int t = 0; t < TT; ++t) {
        const int* pop_t = pop + t * BKR;
        ij_emb_kernel<<<256, 256, 0, stream>>>(W_emb, b_emb, pop_t, EMB);

        ij_gemm_f16x3<<<dim3(64, 4, 2), 256, 0, stream>>>(
            EMB, x_f3 + (size_t)t * BKR * 2048, H, 128, 2176, 128, 2048, 2048,
            W_ih + 2048, W_hh, 2176, 4224, 2048,
            Z, G4, 2112);

        ij_lstm_kernel<<<4096, 256, 0, stream>>>(Z, Z1, XFW, BIAS, Cc, H2, C2);

        ij_gemm_f16x3<<<dim3(16, 4, 4), 256, 0, stream>>>(
            H2, nullptr, nullptr, 1 << 30, 1 << 30, 2048, 0, 0,
            W_fc1, nullptr, 1 << 30, 2048, 0,
            Z, HH, 512);
        ij_reduce_fc1_kernel<<<4096, 256, 0, stream>>>(Z, b_fc1, HD);

        ij_gemm_f16x3<<<dim3(4, 4, 16), 256, 0, stream>>>(
            HD, nullptr, nullptr, 1 << 30, 1 << 30, 2048, 0, 0,
            W_out, nullptr, 1 << 30, 2048, 0,
            Z, DD, 128);

        ij_softmax_g_kernel<<<512, 256, 0, stream>>>(
            Z, b_out, mask, pop_t, gum + (size_t)t * BKR * DD,
            Gv, LOGP, LPT, GMAT, GREEDY);

        ij_beam_kernel<<<64, 256, 0, stream>>>(
            GMAT, LPT, GREEDY, pop_t, mask,
            Gv, LOGP, SAMP, OUTS, ENT, WPQ, LGP, ORDER, t);

        ij_permute_kernel<<<4096, 256, 0, stream>>>(H2, C2, ORDER, H, Cc);
    }

    ij_final_kernel<<<25, 256, 0, stream>>>(OUTS, SAMP, ENT, WPQ, LGP, out);
    (void)in_sizes; (void)n_in; (void)out_size;
}

// Round 4
// 3236.968 us; speedup vs baseline: 1.1443x; 1.0300x over previous
//
#include <hip/hip_runtime.h>
#include <math.h>

// ---------------------------------------------------------------------------
// ImitateJoint: 12-step beam-search LSTM decoder.
// B=64 images, K=8 beams (BK=512 rows), T=12, H=2048, IN=2048, D=400, E=128.
// Round 6: coalesced LDS-staged weight pre-tiling (fixes 2.15x write
// amplification seen in rocprof: WRITE_SIZE 297MB for 138MB useful), xf3
// packs batched into one launch. GEMM path unchanged from round 5.
// Decision-critical math (softmax, Gumbel g, top-k, entropy) stays fp64.
// ---------------------------------------------------------------------------

#define BB   64
#define KK   8
#define TT   12
#define HH   2048
#define DD   400
#define EE   128
#define BKR  512          // B*K rows
#define G4   8192         // 4*H

// ---- OLD (fallback) workspace layout (byte offsets) -----------------------
static const size_t OFF_STATE = 0;                // doubles, 14272 used
static const size_t OFF_H     = 114688;           // float [512][2048]
static const size_t OFF_C     = 4308992;          // float [512][2048]
static const size_t ZERO_END  = 8503296;          // memset 0 .. here
static const size_t OFF_Z     = 8503296;          // float, 2*512*8192 partials
static const size_t OFF_H2    = 42057728;         // float [512][2048]
static const size_t OFF_C2    = 46252032;         // float [512][2048]
static const size_t OFF_HD    = 50446336;         // float [512][2048]
static const size_t OFF_EMB   = 54640640;         // float [512][128]
static const size_t OFF_XFW   = 54902784;         // float [64][8192]
static const size_t OFF_BIAS  = 56999936;         // float [8192]
static const size_t OFF_LPT   = 57032704;         // double [512][400]
static const size_t OFF_GMAT  = 58671104;         // double [512][400]
static const size_t OFF_INTS  = 60309504;         // int [1024]
static const size_t WS_TOTAL  = 60313600;         // ~57.5 MB

// ---- NEW (pre-split) workspace layout -------------------------------------
// Pre-tiled f16 buffers: unit = half8 (16 B). Chunk tile = 1024 units:
// units [0..511] hi plane, [512..1023] lo plane; unit u = mt*64 + oq*16 + lo16
// <-> (row = blk*128 + mt*16 + lo16, k = c*32 + oq*8 + e).
static const size_t NOFF_STATE = 0;               // doubles, 14272 used
static const size_t NOFF_C     = 114688;          // float [512][2048] (cell)
static const size_t NOFF_A16H  = 4308992;         // half8 [4][64][1024] (h packed)
static const size_t NZERO_END  = 8503296;         // memset 0 .. here
static const size_t NOFF_Z     = 8503296;         // float partials (33.5 MB)
static const size_t NOFF_H2    = 42057728;        // float [512][2048]
static const size_t NOFF_C2    = 46252032;        // float [512][2048]
static const size_t NOFF_XFW   = 50446336;        // float [64][8192]
static const size_t NOFF_BIAS  = 52543488;        // float [8192]
static const size_t NOFF_LPT   = 52576256;        // double [512][400]
static const size_t NOFF_GMAT  = 54214656;        // double [512][400]
static const size_t NOFF_INTS  = 55853056;        // int [1024]
static const size_t NOFF_A16E  = 55857152;        // half8 [4][4][1024]   (emb)
static const size_t NOFF_A16X  = 56119296;        // half8 [12][4][64][1024] (xf3)
static const size_t NOFF_A16F  = 106450944;       // half8 [4][64][1024]  (h2)
static const size_t NOFF_A16D  = 110645248;       // half8 [4][64][1024]  (hd)
static const size_t NOFF_B16G  = 114839552;       // half8 [64][132][1024] (Wih|Whh)
static const size_t NOFF_B16F  = 253251584;       // half8 [16][64][1024] (Wfc1)
static const size_t NOFF_B16O  = 270028800;       // half8 [4][64][1024]  (Wout)
static const size_t NWS_TOTAL  = 274223104;       // ~262 MB

#define SI_G    0
#define SI_LOGP 512
#define SI_SAMP 1024
#define SI_OUTS 7168
#define SI_ENT  13312
#define SI_WPQ  13376
#define SI_LGP  13824

using half8  = __attribute__((ext_vector_type(8))) _Float16;
using floatx4 = __attribute__((ext_vector_type(4))) float;

__device__ __forceinline__ void gload16(const void* g, void* l) {
    __builtin_amdgcn_global_load_lds((__attribute__((address_space(1))) void*)g,
                                     (__attribute__((address_space(3))) void*)l,
                                     16, 0, 0);
}

// split x into f16 hi + f16 lo' (lo' = 2048*(x - hi)), writing lane j of the
// half8 vectors (vectors passed by reference: vector-element references are
// not bindable, so subscripting must happen inside).
__device__ __forceinline__ void split16v(float x, half8& hi, half8& lo, int j) {
    _Float16 h = (_Float16)x;
    hi[j] = h;
    lo[j] = (_Float16)((x - (float)h) * 2048.0f);
}

// ---------------------------------------------------------------------------
// NEW: pre-tiled GEMM. C[z][512][N] partials = A[512,K]*B[N,K]^T.
// A/B are pre-split f16 hi/lo planes in fragment order; staging is pure
// global_load_lds (16B) into linear LDS; ds_read_b128 fragments conflict-free.
// Block 256 thr = 4 waves; tile 128x128; wave tile 64x64 = 4x4 of 16x16x32.
// A: up to 3 pre-tiled segments with chunk boundaries cA1/cA2 (absolute) and
// per-m_blk chunk strides chA*.  z = acc1 + acc2/2048 (identical math to old).
// ---------------------------------------------------------------------------
__global__ __launch_bounds__(256, 2)
void ij_gemm_pk(const half8* __restrict__ A0, const half8* __restrict__ A1,
                const half8* __restrict__ A2, int cA1, int cA2,
                int chA0, int chA1, int chA2,
                const half8* __restrict__ Bt, int totB,
                float* __restrict__ C, int N, int cpz)
{
    __shared__ half8 lds[2048];   // 32 KB: A hi|lo (1024), B hi|lo (1024)

    const int tid  = threadIdx.x;
    const int lane = tid & 63;
    const int wid  = tid >> 6;
    const int n0   = blockIdx.x * 128;
    const int m0   = blockIdx.y * 128;
    const int c0   = blockIdx.z * cpz;
    float* Cout = C + (size_t)blockIdx.z * ((size_t)512 * (size_t)N);

    const int wave_m = wid & 1;
    const int wave_n = wid >> 1;
    const int lo16 = lane & 15;
    const int oq   = lane >> 4;

    floatx4 acc1[4][4], acc2[4][4];
#pragma unroll
    for (int i = 0; i < 4; ++i)
#pragma unroll
        for (int j = 0; j < 4; ++j) { acc1[i][j] = (floatx4)0.f; acc2[i][j] = (floatx4)0.f; }

    for (int c = 0; c < cpz; ++c) {
        const int ca = c0 + c;
        __syncthreads();                       // prior chunk's ds_reads done
        if (wid < 2) {                         // waves 0,1 stage A (16 KB)
            const half8* ap; int cl, st;
            if (ca < cA1)      { ap = A0; cl = ca;       st = chA0; }
            else if (ca < cA2) { ap = A1; cl = ca - cA1; st = chA1; }
            else               { ap = A2; cl = ca - cA2; st = chA2; }
            const half8* src = ap + ((size_t)blockIdx.y * st + cl) * 1024 + lane;
#pragma unroll
            for (int j = 0; j < 8; ++j) {
                const int un = (wid * 8 + j) * 64;
                gload16(src + un, &lds[un]);
            }
        } else {                               // waves 2,3 stage B (16 KB)
            const half8* src = Bt + ((size_t)blockIdx.x * totB + ca) * 1024 + lane;
#pragma unroll
            for (int j = 0; j < 8; ++j) {
                const int un = ((wid - 2) * 8 + j) * 64;
                gload16(src + un, &lds[1024 + un]);
            }
        }
        __syncthreads();                       // drains vmcnt -> LDS ready

        half8 Ahi[4], Alo[4];
#pragma unroll
        for (int mt = 0; mt < 4; ++mt) {
            const int amt = wave_m * 4 + mt;
            Ahi[mt] = lds[amt * 64 + lane];
            Alo[mt] = lds[512 + amt * 64 + lane];
        }
#pragma unroll
        for (int nt = 0; nt < 4; ++nt) {
            const int bnt = wave_n * 4 + nt;
            half8 Bhi = lds[1024 + bnt * 64 + lane];
            half8 Blo = lds[1536 + bnt * 64 + lane];
#pragma unroll
            for (int mt = 0; mt < 4; ++mt) {
                acc1[mt][nt] = __builtin_amdgcn_mfma_f32_16x16x32_f16(Ahi[mt], Bhi, acc1[mt][nt], 0, 0, 0);
                acc2[mt][nt] = __builtin_amdgcn_mfma_f32_16x16x32_f16(Ahi[mt], Blo, acc2[mt][nt], 0, 0, 0);
                acc2[mt][nt] = __builtin_amdgcn_mfma_f32_16x16x32_f16(Alo[mt], Bhi, acc2[mt][nt], 0, 0, 0);
            }
        }
    }

    const float s = 1.0f / 2048.0f;
#pragma unroll
    for (int mt = 0; mt < 4; ++mt) {
        const int rbase = m0 + wave_m * 64 + mt * 16 + oq * 4;
#pragma unroll
        for (int nt = 0; nt < 4; ++nt) {
            const int col = n0 + wave_n * 64 + nt * 16 + lo16;
            if (col >= N) continue;
#pragma unroll
            for (int v = 0; v < 4; ++v) {
                float val = acc1[mt][nt][v] + acc2[mt][nt][v] * s;
                Cout[(size_t)(rbase + v) * N + col] = val;
            }
        }
    }
}

// ---------------------------------------------------------------------------
// NEW round-6: coalesced LDS-staged pre-tiler. One block per (row-block nb,
// chunk c): coalesced float4 reads of the 128x32 f32 sub-tile, hi/lo split in
// registers, LDS image of the 16KB output tile, 4 coalesced 4KB stores.
// Source: up to 2 concatenated K-segments (row-major); a 32-wide chunk never
// straddles a segment boundary (all boundaries are multiples of 32).
// Layout out[nb][gridDim.x][1024]: u = mt*64 + oq*16 + lo16, hi 0..511,
// lo 512..1023 (identical to consumer ij_gemm_pk).
// ---------------------------------------------------------------------------
__global__ __launch_bounds__(256)
void ij_pack_w2(const float* __restrict__ S0, const float* __restrict__ S1,
                int kS1, int ld0, int ld1, int Nw, half8* __restrict__ out)
{
    __shared__ half8 sh[1024];       // 16 KB: tile image, hi|lo
    const int c   = blockIdx.x;      // k-chunk
    const int nb  = blockIdx.y;      // 128-row block
    const int tid = threadIdx.x;
    const int R   = tid >> 1;        // row in tile 0..127
    const int o2  = (tid & 1) * 2;   // first of two k-octets

    const int row = nb * 128 + R;
    const int k0  = c * 32 + o2 * 8; // 16 consecutive floats
    const float* sp; int ko, ld;
    if (k0 < kS1) { sp = S0; ko = k0;       ld = ld0; }
    else          { sp = S1; ko = k0 - kS1; ld = ld1; }

    float x[16];
    if (row < Nw) {
        const float* p = sp + (size_t)row * ld + ko;
        const float4 a0 = *(const float4*)(p);
        const float4 a1 = *(const float4*)(p + 4);
        const float4 a2 = *(const float4*)(p + 8);
        const float4 a3 = *(const float4*)(p + 12);
        x[0]=a0.x; x[1]=a0.y; x[2]=a0.z; x[3]=a0.w;
        x[4]=a1.x; x[5]=a1.y; x[6]=a1.z; x[7]=a1.w;
        x[8]=a2.x; x[9]=a2.y; x[10]=a2.z; x[11]=a2.w;
        x[12]=a3.x; x[13]=a3.y; x[14]=a3.z; x[15]=a3.w;
    } else {
#pragma unroll
        for (int j = 0; j < 16; ++j) x[j] = 0.f;
    }

    const int mt = R >> 4, lo16 = R & 15;
#pragma unroll
    for (int q = 0; q < 2; ++q) {
        half8 hi8, lo8;
#pragma unroll
        for (int j = 0; j < 8; ++j) split16v(x[q * 8 + j], hi8, lo8, j);
        const int u = mt * 64 + (o2 + q) * 16 + lo16;
        sh[u]       = hi8;
        sh[512 + u] = lo8;
    }
    __syncthreads();

    const size_t base = ((size_t)nb * gridDim.x + c) * 1024;
#pragma unroll
    for (int j = 0; j < 4; ++j)
        out[base + j * 256 + tid] = sh[j * 256 + tid];
}

// emb = relu(W_emb[:,pop] + b_emb), packed directly into A16E tiles (small).
__global__ void ij_pack_emb(const float* __restrict__ W_emb, const float* __restrict__ b_emb,
                            const int* __restrict__ pop_t, half8* __restrict__ out)
{
    int gid = blockIdx.x * 256 + threadIdx.x;
    if (gid >= BKR * 16) return;             // 512 rows x 16 k-octets
    const int koct = gid & 15;
    const int row  = gid >> 4;
    const int c  = koct >> 2;
    const int oqq = koct & 3;
    const int k0 = koct * 8;
    const int nb = row >> 7, mt = (row >> 4) & 7, lo16 = row & 15;
    const int u  = mt * 64 + oqq * 16 + lo16;
    const int p  = pop_t[row];

    half8 hi8, lo8;
#pragma unroll
    for (int e = 0; e < 8; ++e) {
        const int col = k0 + e;
        float v = W_emb[col * DD + p] + b_emb[col];
        v = v > 0.f ? v : 0.f;
        split16v(v, hi8, lo8, e);
    }
    const size_t base = ((size_t)nb * 4 + c) * 1024;
    out[base + u]       = hi8;
    out[base + 512 + u] = lo8;
}

// LSTM elementwise, 8 elems/thread; fuses gate split-K reduce + xfW + bias,
// writes h2/c2 f32 and packs h2 into A16F (fc1 A-operand).
__global__ void ij_lstm_pk(const float* __restrict__ z0, const float* __restrict__ z1,
                           const float* __restrict__ xfw, const float* __restrict__ bias,
                           const float* __restrict__ c,
                           float* __restrict__ h2, float* __restrict__ c2,
                           half8* __restrict__ a16f)
{
    int gid = blockIdx.x * 256 + threadIdx.x;
    if (gid >= BKR * 256) return;
    const int r   = gid >> 8;
    const int oct = gid & 255;
    const int hh0 = oct * 8;
    const size_t zb = (size_t)r * G4;
    const float* xw = xfw + (size_t)(r & 63) * G4;

    float zg[4][8];
#pragma unroll
    for (int g = 0; g < 4; ++g) {
        const int base = g * HH + hh0;
        const float4 a0 = *(const float4*)(z0 + zb + base);
        const float4 a1 = *(const float4*)(z0 + zb + base + 4);
        const float4 b0 = *(const float4*)(z1 + zb + base);
        const float4 b1 = *(const float4*)(z1 + zb + base + 4);
        const float4 w0 = *(const float4*)(xw + base);
        const float4 w1 = *(const float4*)(xw + base + 4);
        const float4 s0 = *(const float4*)(bias + base);
        const float4 s1 = *(const float4*)(bias + base + 4);
        zg[g][0] = a0.x + b0.x + w0.x + s0.x;  zg[g][1] = a0.y + b0.y + w0.y + s0.y;
        zg[g][2] = a0.z + b0.z + w0.z + s0.z;  zg[g][3] = a0.w + b0.w + w0.w + s0.w;
        zg[g][4] = a1.x + b1.x + w1.x + s1.x;  zg[g][5] = a1.y + b1.y + w1.y + s1.y;
        zg[g][6] = a1.z + b1.z + w1.z + s1.z;  zg[g][7] = a1.w + b1.w + w1.w + s1.w;
    }
    const size_t ib = (size_t)r * HH + hh0;
    const float4 cp0 = *(const float4*)(c + ib);
    const float4 cp1 = *(const float4*)(c + ib + 4);
    float cprev[8] = {cp0.x, cp0.y, cp0.z, cp0.w, cp1.x, cp1.y, cp1.z, cp1.w};

    float h2v[8], c2v[8];
#pragma unroll
    for (int e = 0; e < 8; ++e) {
        float si = 1.f / (1.f + expf(-zg[0][e]));
        float sf = 1.f / (1.f + expf(-zg[1][e]));
        float gt = tanhf(zg[2][e]);
        float so = 1.f / (1.f + expf(-zg[3][e]));
        float cv = sf * cprev[e] + si * gt;
        c2v[e] = cv;
        h2v[e] = so * tanhf(cv);
    }
    *(float4*)(c2 + ib)     = make_float4(c2v[0], c2v[1], c2v[2], c2v[3]);
    *(float4*)(c2 + ib + 4) = make_float4(c2v[4], c2v[5], c2v[6], c2v[7]);
    *(float4*)(h2 + ib)     = make_float4(h2v[0], h2v[1], h2v[2], h2v[3]);
    *(float4*)(h2 + ib + 4) = make_float4(h2v[4], h2v[5], h2v[6], h2v[7]);

    half8 hi8, lo8;
#pragma unroll
    for (int e = 0; e < 8; ++e) split16v(h2v[e], hi8, lo8, e);
    const int cch = oct >> 2, oqq = oct & 3;
    const int mt = (r >> 4) & 7, lo16 = r & 15;
    const size_t base = ((size_t)(r >> 7) * 64 + cch) * 1024;
    const int u = mt * 64 + oqq * 16 + lo16;
    a16f[base + u]       = hi8;
    a16f[base + 512 + u] = lo8;
}

// fc1 reduce (8 split-K partials) + bias + relu, packed into A16D.
__global__ void ij_reduce_fc1_pk(const float* __restrict__ part, const float* __restrict__ b_fc1,
                                 half8* __restrict__ a16d)
{
    int gid = blockIdx.x * 256 + threadIdx.x;
    if (gid >= BKR * 256) return;
    const int r   = gid >> 8;
    const int oct = gid & 255;
    const int hh0 = oct * 8;
    const size_t i = (size_t)r * HH + hh0;

    float v[8];
    {
        const float4 b0 = *(const float4*)(b_fc1 + hh0);
        const float4 b1 = *(const float4*)(b_fc1 + hh0 + 4);
        v[0]=b0.x; v[1]=b0.y; v[2]=b0.z; v[3]=b0.w; v[4]=b1.x; v[5]=b1.y; v[6]=b1.z; v[7]=b1.w;
    }
#pragma unroll
    for (int s = 0; s < 8; ++s) {
        const float4 p0 = *(const float4*)(part + (size_t)s * 1048576 + i);
        const float4 p1 = *(const float4*)(part + (size_t)s * 1048576 + i + 4);
        v[0]+=p0.x; v[1]+=p0.y; v[2]+=p0.z; v[3]+=p0.w; v[4]+=p1.x; v[5]+=p1.y; v[6]+=p1.z; v[7]+=p1.w;
    }
    half8 hi8, lo8;
#pragma unroll
    for (int e = 0; e < 8; ++e) {
        float x = v[e] > 0.f ? v[e] : 0.f;
        split16v(x, hi8, lo8, e);
    }
    const int cch = oct >> 2, oqq = oct & 3;
    const int mt = (r >> 4) & 7, lo16 = r & 15;
    const size_t base = ((size_t)(r >> 7) * 64 + cch) * 1024;
    const int u = mt * 64 + oqq * 16 + lo16;
    a16d[base + u]       = hi8;
    a16d[base + 512 + u] = lo8;
}

// beam-order permute: c <- c2[order], and h2[order] packed into A16H.
__global__ void ij_permute_pk(const float* __restrict__ h2, const float* __restrict__ c2,
                              const int* __restrict__ order_g,
                              float* __restrict__ c, half8* __restrict__ a16h)
{
    int gid = blockIdx.x * 256 + threadIdx.x;
    if (gid >= BKR * 256) return;
    const int r   = gid >> 8;
    const int oct = gid & 255;
    const int hh0 = oct * 8;
    const int o   = order_g[r];
    const size_t so_ = (size_t)o * HH + hh0;
    const size_t di  = (size_t)r * HH + hh0;

    const float4 cc0 = *(const float4*)(c2 + so_);
    const float4 cc1 = *(const float4*)(c2 + so_ + 4);
    *(float4*)(c + di)     = cc0;
    *(float4*)(c + di + 4) = cc1;

    const float4 hh0v = *(const float4*)(h2 + so_);
    const float4 hh1v = *(const float4*)(h2 + so_ + 4);
    float hv[8] = {hh0v.x, hh0v.y, hh0v.z, hh0v.w, hh1v.x, hh1v.y, hh1v.z, hh1v.w};
    half8 hi8, lo8;
#pragma unroll
    for (int e = 0; e < 8; ++e) split16v(hv[e], hi8, lo8, e);
    const int cch = oct >> 2, oqq = oct & 3;
    const int mt = (r >> 4) & 7, lo16 = r & 15;
    const size_t base = ((size_t)(r >> 7) * 64 + cch) * 1024;
    const int u = mt * 64 + oqq * 16 + lo16;
    a16h[base + u]       = hi8;
    a16h[base + 512 + u] = lo8;
}

// ---------------------------------------------------------------------------
// OLD (fallback) f16-split reg-staging GEMM — verified round-3 kernel.
// ---------------------------------------------------------------------------
__global__ __launch_bounds__(256, 2)
void ij_gemm_f16x3(const float* __restrict__ A0, const float* __restrict__ A1,
                   const float* __restrict__ A2, int kA1, int kA2,
                   int lda0, int lda1, int lda2,
                   const float* __restrict__ B0, const float* __restrict__ B1,
                   int kB1, int ldb0, int ldb1,
                   float* __restrict__ C, int N, int Klen)
{
    __shared__ half8 lds[2048];

    const int tid = threadIdx.x;
    const int n0  = blockIdx.x * 128;
    const int m0  = blockIdx.y * 128;
    const int kstart = blockIdx.z * Klen;
    const int nch = Klen / 32;
    float* Cout = C + (size_t)blockIdx.z * ((size_t)512 * (size_t)N);

    const int wid    = tid >> 6;
    const int wave_m = wid & 1;
    const int wave_n = wid >> 1;
    const int lane   = tid & 63;
    const int lo16   = lane & 15;
    const int oq     = lane >> 4;
    const int laneSlot = oq * 16 + ((lo16 + 4 * oq) & 15);

    const int st_o   = tid & 3;
    const int st_row0 = tid >> 2;

    float4 pfA[2][2], pfB[2][2];

    auto loadGlobals = [&](int c) {
        const int kb = kstart + c * 32;
#pragma unroll
        for (int i = 0; i < 2; ++i) {
            const int row = st_row0 + i * 64;
            const int kc  = kb + st_o * 8;
            const float* ap; int ao, ld;
            if (kc < kA1)      { ap = A0; ao = kc;       ld = lda0; }
            else if (kc < kA2) { ap = A1; ao = kc - kA1; ld = lda1; }
            else               { ap = A2; ao = kc - kA2; ld = lda2; }
            const float* p = ap + (size_t)(m0 + row) * ld + ao;
            pfA[i][0] = *(const float4*)(p);
            pfA[i][1] = *(const float4*)(p + 4);
            const int bn = n0 + row;
            const float* bp; int bo, bld;
            if (kc < kB1) { bp = B0; bo = kc;       bld = ldb0; }
            else          { bp = B1; bo = kc - kB1; bld = ldb1; }
            if (bn < N) {
                const float* q = bp + (size_t)bn * bld + bo;
                pfB[i][0] = *(const float4*)(q);
                pfB[i][1] = *(const float4*)(q + 4);
            } else {
                pfB[i][0] = make_float4(0.f,0.f,0.f,0.f);
                pfB[i][1] = make_float4(0.f,0.f,0.f,0.f);
            }
        }
    };

    auto writeLDS = [&]() {
#pragma unroll
        for (int i = 0; i < 2; ++i) {
            const int row = st_row0 + i * 64;
            const int mt  = row >> 4;
            const int idx = mt * 64 + st_o * 16 + (((row & 15) + 4 * st_o) & 15);
            {
                float x[8] = {pfA[i][0].x, pfA[i][0].y, pfA[i][0].z, pfA[i][0].w,
                              pfA[i][1].x, pfA[i][1].y, pfA[i][1].z, pfA[i][1].w};
                half8 hi8, lo8;
#pragma unroll
                for (int j = 0; j < 8; ++j) split16v(x[j], hi8, lo8, j);
                lds[idx]       = hi8;
                lds[512 + idx] = lo8;
            }
            {
                float x[8] = {pfB[i][0].x, pfB[i][0].y, pfB[i][0].z, pfB[i][0].w,
                              pfB[i][1].x, pfB[i][1].y, pfB[i][1].z, pfB[i][1].w};
                half8 hi8, lo8;
#pragma unroll
                for (int j = 0; j < 8; ++j) split16v(x[j], hi8, lo8, j);
                lds[1024 + idx] = hi8;
                lds[1536 + idx] = lo8;
            }
        }
    };

    floatx4 acc1[4][4], acc2[4][4];
#pragma unroll
    for (int i = 0; i < 4; ++i)
#pragma unroll
        for (int j = 0; j < 4; ++j) { acc1[i][j] = (floatx4)0.f; acc2[i][j] = (floatx4)0.f; }

    loadGlobals(0);
    for (int c = 0; c < nch; ++c) {
        __syncthreads();
        writeLDS();
        __syncthreads();
        if (c + 1 < nch) loadGlobals(c + 1);

        half8 Ahi[4], Alo[4];
#pragma unroll
        for (int mt = 0; mt < 4; ++mt) {
            const int amt = wave_m * 4 + mt;
            Ahi[mt] = lds[amt * 64 + laneSlot];
            Alo[mt] = lds[512 + amt * 64 + laneSlot];
        }
#pragma unroll
        for (int nt = 0; nt < 4; ++nt) {
            const int bnt = wave_n * 4 + nt;
            half8 Bhi = lds[1024 + bnt * 64 + laneSlot];
            half8 Blo = lds[1536 + bnt * 64 + laneSlot];
#pragma unroll
            for (int mt = 0; mt < 4; ++mt) {
                acc1[mt][nt] = __builtin_amdgcn_mfma_f32_16x16x32_f16(Ahi[mt], Bhi, acc1[mt][nt], 0, 0, 0);
                acc2[mt][nt] = __builtin_amdgcn_mfma_f32_16x16x32_f16(Ahi[mt], Blo, acc2[mt][nt], 0, 0, 0);
                acc2[mt][nt] = __builtin_amdgcn_mfma_f32_16x16x32_f16(Alo[mt], Bhi, acc2[mt][nt], 0, 0, 0);
            }
        }
    }

    const float s = 1.0f / 2048.0f;
#pragma unroll
    for (int mt = 0; mt < 4; ++mt) {
        const int rbase = m0 + wave_m * 64 + mt * 16 + oq * 4;
#pragma unroll
        for (int nt = 0; nt < 4; ++nt) {
            const int col = n0 + wave_n * 64 + nt * 16 + lo16;
            if (col >= N) continue;
#pragma unroll
            for (int v = 0; v < 4; ++v) {
                float val = acc1[mt][nt][v] + acc2[mt][nt][v] * s;
                Cout[(size_t)(rbase + v) * N + col] = val;
            }
        }
    }
}

// ---------------------------------------------------------------------------
// fp32 vector GEMM (one-time xfW precompute, M=64).
// ---------------------------------------------------------------------------
#define FBM 128
#define FBN 64
#define FBK 16

__global__ __launch_bounds__(256, 2)
void ij_gemm_f32(const float* __restrict__ A0, const float* __restrict__ A1,
                 const float* __restrict__ A2, int kA1, int kA2,
                 int lda0, int lda1, int lda2,
                 const float* __restrict__ B0, const float* __restrict__ B1,
                 int kB1, int ldb0, int ldb1,
                 float* __restrict__ C, int M, int N, int Klen)
{
    __shared__ float As[2][FBK][FBM];
    __shared__ float Bs[2][FBK][FBN];

    const int tid = threadIdx.x;
    const int tx  = tid & 15;
    const int ty  = tid >> 4;
    const int n0  = blockIdx.x * FBN;
    const int m0  = blockIdx.y * FBM;
    const int kstart = blockIdx.z * Klen;
    const int nch = Klen / FBK;
    float* Cout = C + (size_t)blockIdx.z * ((size_t)M * (size_t)N);

    const int srow = tid >> 2;
    const int kq   = tid & 3;

    float4 aR0, aR1, bR;

    auto loadChunk = [&](int kb0) {
        const int kc = kb0 + kq * 4;
        const float* ap; int ao, ld;
        if (kc < kA1)      { ap = A0; ao = kc;       ld = lda0; }
        else if (kc < kA2) { ap = A1; ao = kc - kA1; ld = lda1; }
        else               { ap = A2; ao = kc - kA2; ld = lda2; }
        const int r0 = m0 + srow, r1 = r0 + 64;
        aR0 = (r0 < M) ? *(const float4*)(ap + (size_t)r0 * ld + ao)
                       : make_float4(0.f, 0.f, 0.f, 0.f);
        aR1 = (r1 < M) ? *(const float4*)(ap + (size_t)r1 * ld + ao)
                       : make_float4(0.f, 0.f, 0.f, 0.f);
        const float* bp; int bo, bld;
        if (kc < kB1) { bp = B0; bo = kc;       bld = ldb0; }
        else          { bp = B1; bo = kc - kB1; bld = ldb1; }
        const int bn = n0 + srow;
        bR = (bn < N) ? *(const float4*)(bp + (size_t)bn * bld + bo)
                      : make_float4(0.f, 0.f, 0.f, 0.f);
    };
    auto storeChunk = [&](int bsel) {
        const int k4 = kq * 4;
        As[bsel][k4+0][srow]      = aR0.x;
        As[bsel][k4+1][srow]      = aR0.y;
        As[bsel][k4+2][srow]      = aR0.z;
        As[bsel][k4+3][srow]      = aR0.w;
        As[bsel][k4+0][srow + 64] = aR1.x;
        As[bsel][k4+1][srow + 64] = aR1.y;
        As[bsel][k4+2][srow + 64] = aR1.z;
        As[bsel][k4+3][srow + 64] = aR1.w;
        Bs[bsel][k4+0][srow]      = bR.x;
        Bs[bsel][k4+1][srow]      = bR.y;
        Bs[bsel][k4+2][srow]      = bR.z;
        Bs[bsel][k4+3][srow]      = bR.w;
    };

    float acc[8][4];
#pragma unroll
    for (int i = 0; i < 8; ++i)
#pragma unroll
        for (int j = 0; j < 4; ++j) acc[i][j] = 0.f;

    loadChunk(kstart);
    storeChunk(0);
    __syncthreads();
    int bsel = 0;
    for (int c = 0; c < nch; ++c) {
        if (c + 1 < nch) loadChunk(kstart + (c + 1) * FBK);
#pragma unroll
        for (int kkk = 0; kkk < FBK; ++kkk) {
            float a[8], b[4];
            const float4 av0 = *(const float4*)&As[bsel][kkk][ty * 8];
            const float4 av1 = *(const float4*)&As[bsel][kkk][ty * 8 + 4];
            a[0]=av0.x; a[1]=av0.y; a[2]=av0.z; a[3]=av0.w;
            a[4]=av1.x; a[5]=av1.y; a[6]=av1.z; a[7]=av1.w;
            const float2 bv0 = *(const float2*)&Bs[bsel][kkk][tx * 2];
            const float2 bv1 = *(const float2*)&Bs[bsel][kkk][tx * 2 + 32];
            b[0]=bv0.x; b[1]=bv0.y; b[2]=bv1.x; b[3]=bv1.y;
#pragma unroll
            for (int i = 0; i < 8; ++i)
#pragma unroll
                for (int j = 0; j < 4; ++j)
                    acc[i][j] = fmaf(a[i], b[j], acc[i][j]);
        }
        if (c + 1 < nch) storeChunk(bsel ^ 1);
        __syncthreads();
        bsel ^= 1;
    }

#pragma unroll
    for (int i = 0; i < 8; ++i) {
        const int row = m0 + ty * 8 + i;
        if (row >= M) continue;
        const size_t rbase = (size_t)row * N;
#pragma unroll
        for (int g = 0; g < 2; ++g) {
            const int col = n0 + tx * 2 + g * 32;
            if (col + 1 < N) {
                float2 st; st.x = acc[i][g*2+0]; st.y = acc[i][g*2+1];
                *(float2*)(Cout + rbase + col) = st;
            } else if (col < N) {
                Cout[rbase + col] = acc[i][g*2+0];
            }
        }
    }
}

// ---------------------------------------------------------------------------
__global__ void ij_bias_kernel(const float* __restrict__ b_ih, const float* __restrict__ b_hh,
                               float* __restrict__ bias)
{
    int i = blockIdx.x * 256 + threadIdx.x;
    if (i < G4) bias[i] = b_ih[i] + b_hh[i];
}

__global__ void ij_emb_kernel(const float* __restrict__ W_emb, const float* __restrict__ b_emb,
                              const int* __restrict__ pop_t, float* __restrict__ emb)
{
    int i = blockIdx.x * 256 + threadIdx.x;
    if (i >= BKR * EE) return;
    int r = i >> 7, e = i & 127;
    float v = W_emb[e * DD + pop_t[r]] + b_emb[e];
    emb[i] = v > 0.f ? v : 0.f;
}

// OLD fallback LSTM elementwise (split-K=2 reduce + xfW + bias).
__global__ void ij_lstm_kernel(const float* __restrict__ z0, const float* __restrict__ z1,
                               const float* __restrict__ xfw, const float* __restrict__ bias,
                               const float* __restrict__ c,
                               float* __restrict__ h2, float* __restrict__ c2)
{
    int i = blockIdx.x * 256 + threadIdx.x;
    if (i >= BKR * HH) return;
    int r = i >> 11, hh = i & 2047;
    const size_t zb = (size_t)r * G4;
    const float* xw = xfw + (size_t)(r & 63) * G4;
    float iv = z0[zb + hh]        + z1[zb + hh]        + xw[hh]        + bias[hh];
    float fv = z0[zb + HH + hh]   + z1[zb + HH + hh]   + xw[HH + hh]   + bias[HH + hh];
    float gv = z0[zb + 2*HH + hh] + z1[zb + 2*HH + hh] + xw[2*HH + hh] + bias[2*HH + hh];
    float ov = z0[zb + 3*HH + hh] + z1[zb + 3*HH + hh] + xw[3*HH + hh] + bias[3*HH + hh];
    float si = 1.f / (1.f + expf(-iv));
    float sf = 1.f / (1.f + expf(-fv));
    float so = 1.f / (1.f + expf(-ov));
    float cv = sf * c[i] + si * tanhf(gv);
    c2[i] = cv;
    h2[i] = so * tanhf(cv);
}

__global__ void ij_reduce_fc1_kernel(const float* __restrict__ part, const float* __restrict__ b_fc1,
                                     float* __restrict__ hd)
{
    int i = blockIdx.x * 256 + threadIdx.x;
    if (i >= BKR * HH) return;
    float v = part[i] + part[i + 1048576] + part[i + 2097152] + part[i + 3145728]
            + b_fc1[i & 2047];
    hd[i] = v > 0.f ? v : 0.f;
}

__global__ void ij_reduce_xfw_kernel(const float* __restrict__ part, float* __restrict__ xfw)
{
    int i = blockIdx.x * 256 + threadIdx.x;
    if (i >= BB * G4) return;
    xfw[i] = part[i] + part[i + 524288] + part[i + 1048576] + part[i + 1572864];
}

// ---------------------------------------------------------------------------
// Per-row: reduce 16 logits partials + b_out + mask row, log_softmax, greedy
// argmax, Gumbel-with-max conditioned g. All f64 (decision-critical).
// ---------------------------------------------------------------------------
__global__ __launch_bounds__(256)
void ij_softmax_g_kernel(const float* __restrict__ part, const float* __restrict__ b_out,
                         const float* __restrict__ mask_table, const int* __restrict__ pop_t,
                         const float* __restrict__ gum_t, const double* __restrict__ G,
                         const double* __restrict__ logp,
                         double* __restrict__ logp_tok, double* __restrict__ gmat,
                         int* __restrict__ greedy)
{
    const int r = blockIdx.x, tid = threadIdx.x;
    __shared__ double sred[256];
    __shared__ int    sidx[256];
    __shared__ double sbc[2];

    const int pop = pop_t[r];
    const int j0 = tid, j1 = tid + 256;
    double lg0 = -INFINITY, lg1 = -INFINITY;
    if (j0 < DD) {
        double v = (double)b_out[j0] + (double)mask_table[pop * DD + j0];
#pragma unroll
        for (int s = 0; s < 16; ++s) v += (double)part[(size_t)s * (BKR*DD) + (size_t)r * DD + j0];
        lg0 = v;
    }
    if (j1 < DD) {
        double v = (double)b_out[j1] + (double)mask_table[pop * DD + j1];
#pragma unroll
        for (int s = 0; s < 16; ++s) v += (double)part[(size_t)s * (BKR*DD) + (size_t)r * DD + j1];
        lg1 = v;
    }
    double mv = lg0; int mi = j0;
    if (lg1 > mv) { mv = lg1; mi = j1; }
    sred[tid] = mv; sidx[tid] = mi;
    __syncthreads();
    for (int off = 128; off > 0; off >>= 1) {
        if (tid < off) {
            double ov = sred[tid+off]; int oi = sidx[tid+off];
            if (ov > sred[tid] || (ov == sred[tid] && oi < sidx[tid])) { sred[tid] = ov; sidx[tid] = oi; }
        }
        __syncthreads();
    }
    if (tid == 0) { sbc[0] = sred[0]; greedy[r] = sidx[0]; }
    __syncthreads();
    const double rowmax = sbc[0];

    double es = 0.0;
    if (j0 < DD) es += exp(lg0 - rowmax);
    if (j1 < DD) es += exp(lg1 - rowmax);
    __syncthreads();
    sred[tid] = es;
    __syncthreads();
    for (int off = 128; off > 0; off >>= 1) {
        if (tid < off) sred[tid] += sred[tid+off];
        __syncthreads();
    }
    if (tid == 0) sbc[1] = log(sred[0]);
    __syncthreads();
    const double lse = sbc[1];
    const double lpr = logp[r], Gr = G[r];

    double gp0 = -INFINITY, gp1 = -INFINITY;
    if (j0 < DD) {
        double lt = lg0 - rowmax - lse;
        logp_tok[(size_t)r * DD + j0] = lt;
        double u = (double)gum_t[(size_t)r * DD + j0];
        u = fmin(fmax(u, 1e-9), 1.0 - 1e-9);
        gp0 = lt + lpr + (-log(-log(u)));
    }
    if (j1 < DD) {
        double lt = lg1 - rowmax - lse;
        logp_tok[(size_t)r * DD + j1] = lt;
        double u = (double)gum_t[(size_t)r * DD + j1];
        u = fmin(fmax(u, 1e-9), 1.0 - 1e-9);
        gp1 = lt + lpr + (-log(-log(u)));
    }
    __syncthreads();
    sred[tid] = fmax(gp0, gp1);
    __syncthreads();
    for (int off = 128; off > 0; off >>= 1) {
        if (tid < off) sred[tid] = fmax(sred[tid], sred[tid+off]);
        __syncthreads();
    }
    const double Z = sred[0];
    if (j0 < DD) {
        double v = Gr - gp0 + log1p(-exp(gp0 - Z));
        gmat[(size_t)r * DD + j0] = Gr - fmax(v, 0.0) - log1p(exp(-fabs(v)));
    }
    if (j1 < DD) {
        double v = Gr - gp1 + log1p(-exp(gp1 - Z));
        gmat[(size_t)r * DD + j1] = Gr - fmax(v, 0.0) - log1p(exp(-fabs(v)));
    }
}

// ---------------------------------------------------------------------------
// One block per image b: top-8 of 3200 (desc, low index on tie), bookkeeping.
// ---------------------------------------------------------------------------
__global__ __launch_bounds__(256)
void ij_beam_kernel(const double* __restrict__ gmat, const double* __restrict__ logp_tok,
                    const int* __restrict__ greedy, const int* __restrict__ pop_t,
                    const float* __restrict__ mask_table,
                    double* __restrict__ G, double* __restrict__ logp,
                    double* __restrict__ samples, double* __restrict__ outs,
                    double* __restrict__ entacc, double* __restrict__ wpq,
                    double* __restrict__ lgp_o, int* __restrict__ order_g, int t)
{
    const int b = blockIdx.x, tid = threadIdx.x;
    __shared__ double sv[256];
    __shared__ int    si2[256];
    __shared__ double gval8[8];
    __shared__ int    gidx8[8];
    __shared__ int    ord8[8], smp8[8];
    __shared__ double lp28[8], sel8[8], Gn8[8];
    __shared__ double oldS[8][TT], oldO[8][TT];
    __shared__ double efull[8];

    if (t > 0) {
        for (int pass = 0; pass < 8; ++pass) {
            double bv = -INFINITY; int bi = 0x7fffffff;
            for (int cand = tid; cand < KK * DD; cand += 256) {
                bool used = false;
                for (int p = 0; p < pass; ++p) used |= (gidx8[p] == cand);
                if (used) continue;
                int kb2 = cand / DD, d = cand - kb2 * DD;
                double v = gmat[(size_t)(kb2 * BB + b) * DD + d];
                if (v > bv || (v == bv && cand < bi)) { bv = v; bi = cand; }
            }
            sv[tid] = bv; si2[tid] = bi;
            __syncthreads();
            for (int off = 128; off > 0; off >>= 1) {
                if (tid < off) {
                    double ov = sv[tid+off]; int oi = si2[tid+off];
                    if (ov > sv[tid] || (ov == sv[tid] && oi < si2[tid])) { sv[tid] = ov; si2[tid] = oi; }
                }
                __syncthreads();
            }
            if (tid == 0) { gval8[pass] = sv[0]; gidx8[pass] = si2[0]; }
            __syncthreads();
        }
    }

    if (tid < 8) {
        const int s = tid, rp = s * BB + b;
        int ord, smp; double Gn;
        if (t == 0) { ord = rp; smp = greedy[rp]; Gn = G[rp]; }
        else {
            int idx = gidx8[s]; int kb2 = idx / DD;
            ord = kb2 * BB + b; smp = idx - kb2 * DD; Gn = gval8[s];
        }
        ord8[s] = ord; smp8[s] = smp; Gn8[s] = Gn;
        double sel = logp_tok[(size_t)ord * DD + smp];
        double lp2 = (t == 0) ? logp[ord] : logp[ord] + sel;
        sel8[s] = sel; lp28[s] = lp2;
    }
    __syncthreads();
    if (tid < 8 * TT) {
        int s = tid / TT, ttc = tid - s * TT;
        oldS[s][ttc] = samples[ord8[s] * TT + ttc];
        oldO[s][ttc] = outs[ord8[s] * TT + ttc];
    }
    __syncthreads();
    if (tid < 8 * TT) {
        int s = tid / TT, ttc = tid - s * TT;
        int rp = s * BB + b;
        samples[rp * TT + ttc] = (ttc == t) ? (double)smp8[s] : oldS[s][ttc];
        outs[rp * TT + ttc]    = (ttc == t) ? sel8[s]         : oldO[s][ttc];
    }
    if (tid >= 96 && tid < 104) {
        int s = tid - 96, rp = s * BB + b;
        G[rp]       = Gn8[s];
        logp[rp]    = lp28[s];
        order_g[rp] = ord8[s];
    }

    if (t > 0) {
        for (int s = 0; s < KK - 1; ++s) {
            const int ord = ord8[s];
            const double* lrow = logp_tok + (size_t)ord * DD;
            const float*  mrow = mask_table + (size_t)pop_t[ord] * DD;
            double acc = 0.0;
            for (int j = tid; j < DD; j += 256) {
                double lp_ = lrow[j];
                if (mrow[j] == 0.0f) acc += lp_ * exp(lp_);
            }
            __syncthreads();
            sv[tid] = acc;
            __syncthreads();
            for (int off = 128; off > 0; off >>= 1) {
                if (tid < off) sv[tid] += sv[tid+off];
                __syncthreads();
            }
            if (tid == 0) efull[s] = sv[0];
            __syncthreads();
        }
        if (tid == 0) {
            const double gk = gval8[7];
            double sw = 0.0, swe = 0.0;
            for (int s = 0; s < KK - 1; ++s) {
                double phi = lp28[s];
                double x = gk - phi;
                double y = exp(-x);
                double gls;
                if (x >= 10.0) gls = -x - y * 0.5 + y * y * (1.0 / 24.0);
                else           gls = log(-expm1(-exp(-fmin(x, 10.0))));
                double w = exp(phi - gls);
                wpq[b * (KK-1) + s]   = w;
                lgp_o[b * (KK-1) + s] = phi;
                sw += w; swe += w * efull[s];
            }
            entacc[b] += swe / sw;
        }
    }
}

__global__ void ij_permute_kernel(const float* __restrict__ h2, const float* __restrict__ c2,
                                  const int* __restrict__ order_g,
                                  float* __restrict__ h, float* __restrict__ c)
{
    int i = blockIdx.x * 256 + threadIdx.x;
    if (i >= BKR * HH) return;
    int r = i >> 11, j = i & 2047;
    int o = order_g[r];
    h[i] = h2[(size_t)o * HH + j];
    c[i] = c2[(size_t)o * HH + j];
}

__global__ void ij_final_kernel(const double* __restrict__ outs, const double* __restrict__ samples,
                                const double* __restrict__ entacc, const double* __restrict__ wpq,
                                const double* __restrict__ lgp_o, float* __restrict__ out)
{
    int i = blockIdx.x * 256 + threadIdx.x;
    if (i < 5376) {
        int bb = i / 84, rest = i - bb * 84;
        int s = rest / TT, ttc = rest - s * TT;
        size_t src = (size_t)(s * BB + bb) * TT + ttc;
        out[i]        = (float)outs[src];
        out[5376 + i] = (float)samples[src];
    } else if (i < 5440) {
        out[10752 + (i - 5376)] = (float)entacc[i - 5376];
    } else if (i < 5888) {
        int q = i - 5440; out[10816 + q] = (float)wpq[q];
    } else if (i < 6336) {
        int q = i - 5888; out[11264 + q] = (float)lgp_o[q];
    }
}

// ---------------------------------------------------------------------------
extern "C" void kernel_launch(void* const* d_in, const int* in_sizes, int n_in,
                              void* d_out, int out_size, void* d_ws, size_t ws_size,
                              hipStream_t stream)
{
    const float* x_f   = (const float*)d_in[0];
    const float* x_f3  = (const float*)d_in[1];
    const float* gum   = (const float*)d_in[2];
    const int*   pop   = (const int*)d_in[3];
    const float* mask  = (const float*)d_in[4];
    const float* W_emb = (const float*)d_in[5];
    const float* b_emb = (const float*)d_in[6];
    const float* W_ih  = (const float*)d_in[7];
    const float* W_hh  = (const float*)d_in[8];
    const float* b_ih  = (const float*)d_in[9];
    const float* b_hh  = (const float*)d_in[10];
    const float* W_fc1 = (const float*)d_in[11];
    const float* b_fc1 = (const float*)d_in[12];
    const float* W_out = (const float*)d_in[13];
    const float* b_out = (const float*)d_in[14];
    float* out = (float*)d_out;
    char*  ws  = (char*)d_ws;

    if (ws_size >= NWS_TOTAL) {
        // ---------------- NEW pre-split path ----------------
        double* STATE = (double*)(ws + NOFF_STATE);
        double* Gv    = STATE + SI_G;
        double* LOGP  = STATE + SI_LOGP;
        double* SAMP  = STATE + SI_SAMP;
        double* OUTS  = STATE + SI_OUTS;
        double* ENT   = STATE + SI_ENT;
        double* WPQ   = STATE + SI_WPQ;
        double* LGP   = STATE + SI_LGP;
        float*  Cc    = (float*)(ws + NOFF_C);
        half8*  A16H  = (half8*)(ws + NOFF_A16H);
        float*  Z     = (float*)(ws + NOFF_Z);
        float*  Z1    = Z + (size_t)BKR * G4;
        float*  H2    = (float*)(ws + NOFF_H2);
        float*  C2    = (float*)(ws + NOFF_C2);
        float*  XFW   = (float*)(ws + NOFF_XFW);
        float*  BIAS  = (float*)(ws + NOFF_BIAS);
        double* LPT   = (double*)(ws + NOFF_LPT);
        double* GMAT  = (double*)(ws + NOFF_GMAT);
        int*    ORDER = (int*)(ws + NOFF_INTS);
        int*    GREEDY= ORDER + 512;
        half8*  A16E  = (half8*)(ws + NOFF_A16E);
        half8*  A16X  = (half8*)(ws + NOFF_A16X);
        half8*  A16F  = (half8*)(ws + NOFF_A16F);
        half8*  A16D  = (half8*)(ws + NOFF_A16D);
        half8*  B16G  = (half8*)(ws + NOFF_B16G);
        half8*  B16F  = (half8*)(ws + NOFF_B16F);
        half8*  B16O  = (half8*)(ws + NOFF_B16O);

        hipMemsetAsync(ws, 0, NZERO_END, stream);   // STATE + Cc + A16H(h=0)
        ij_bias_kernel<<<32, 256, 0, stream>>>(b_ih, b_hh, BIAS);

        // one-time weight pre-tiling into f16 hi/lo fragment planes
        // (coalesced LDS-staged: one block per 128-row x 32-k tile)
        ij_pack_w2<<<dim3(132, 64), 256, 0, stream>>>(
            W_ih + 2048, W_hh, 2176, 4224, 2048, 8192, B16G);
        ij_pack_w2<<<dim3(64, 16), 256, 0, stream>>>(
            W_fc1, nullptr, 1 << 30, 2048, 0, 2048, B16F);
        ij_pack_w2<<<dim3(64, 4), 256, 0, stream>>>(
            W_out, nullptr, 1 << 30, 2048, 0, 400, B16O);
        // all 12 xf3 slices in one launch: x_f3 is contiguous [12*512][2048];
        // out [48][64][1024] == [12][4][64][1024] (per-t stride 262144)
        ij_pack_w2<<<dim3(64, 48), 256, 0, stream>>>(
            x_f3, nullptr, 1 << 30, 2048, 0, TT * BKR, A16X);

        // xfW = x_f @ W_ih[:, :2048]^T  (one-time fp32 vector GEMM, M=64)
        ij_gemm_f32<<<dim3(128, 1, 4), 256, 0, stream>>>(
            x_f, nullptr, nullptr, 1 << 30, 1 << 30, 2048, 0, 0,
            W_ih, nullptr, 1 << 30, 4224, 0,
            Z, BB, G4, 512);
        ij_reduce_xfw_kernel<<<2048, 256, 0, stream>>>(Z, XFW);

        for (int t = 0; t < TT; ++t) {
            const int* pop_t = pop + t * BKR;
            ij_pack_emb<<<32, 256, 0, stream>>>(W_emb, b_emb, pop_t, A16E);

            // gate GEMM: A=[emb(ch0..3)|xf3_t(ch4..67)|h(ch68..131)], B=B16G
            ij_gemm_pk<<<dim3(64, 4, 2), 256, 0, stream>>>(
                A16E, A16X + (size_t)t * 262144, A16H, 4, 68, 4, 64, 64,
                B16G, 132, Z, G4, 66);

            ij_lstm_pk<<<512, 256, 0, stream>>>(Z, Z1, XFW, BIAS, Cc, H2, C2, A16F);

            // fc1 (split-K=8)
            ij_gemm_pk<<<dim3(16, 4, 8), 256, 0, stream>>>(
                A16F, A16F, A16F, 1 << 30, 1 << 30, 64, 64, 64,
                B16F, 64, Z, HH, 8);
            ij_reduce_fc1_pk<<<512, 256, 0, stream>>>(Z, b_fc1, A16D);

            // logits (split-K=16; reduce folded into softmax kernel)
            ij_gemm_pk<<<dim3(4, 4, 16), 256, 0, stream>>>(
                A16D, A16D, A16D, 1 << 30, 1 << 30, 64, 64, 64,
                B16O, 64, Z, DD, 4);

            ij_softmax_g_kernel<<<512, 256, 0, stream>>>(
                Z, b_out, mask, pop_t, gum + (size_t)t * BKR * DD,
                Gv, LOGP, LPT, GMAT, GREEDY);

            ij_beam_kernel<<<64, 256, 0, stream>>>(
                GMAT, LPT, GREEDY, pop_t, mask,
                Gv, LOGP, SAMP, OUTS, ENT, WPQ, LGP, ORDER, t);

            ij_permute_pk<<<512, 256, 0, stream>>>(H2, C2, ORDER, Cc, A16H);
        }

        ij_final_kernel<<<25, 256, 0, stream>>>(OUTS, SAMP, ENT, WPQ, LGP, out);
        (void)in_sizes; (void)n_in; (void)out_size;
        return;
    }

    // ---------------- OLD fallback path (round-3 verified) ----------------
    if (ws_size < WS_TOTAL) return;

    double* STATE = (double*)(ws + OFF_STATE);
    double* Gv    = STATE + SI_G;
    double* LOGP  = STATE + SI_LOGP;
    double* SAMP  = STATE + SI_SAMP;
    double* OUTS  = STATE + SI_OUTS;
    double* ENT   = STATE + SI_ENT;
    double* WPQ   = STATE + SI_WPQ;
    double* LGP   = STATE + SI_LGP;
    float*  H     = (float*)(ws + OFF_H);
    float*  Cc    = (float*)(ws + OFF_C);
    float*  Z     = (float*)(ws + OFF_Z);
    float*  Z1    = Z + (size_t)BKR * G4;
    float*  H2    = (float*)(ws + OFF_H2);
    float*  C2    = (float*)(ws + OFF_C2);
    float*  HD    = (float*)(ws + OFF_HD);
    float*  EMB   = (float*)(ws + OFF_EMB);
    float*  XFW   = (float*)(ws + OFF_XFW);
    float*  BIAS  = (float*)(ws + OFF_BIAS);
    double* LPT   = (double*)(ws + OFF_LPT);
    double* GMAT  = (double*)(ws + OFF_GMAT);
    int*    ORDER = (int*)(ws + OFF_INTS);
    int*    GREEDY= ORDER + 512;

    hipMemsetAsync(ws, 0, ZERO_END, stream);
    ij_bias_kernel<<<32, 256, 0, stream>>>(b_ih, b_hh, BIAS);

    ij_gemm_f32<<<dim3(128, 1, 4), 256, 0, stream>>>(
        x_f, nullptr, nullptr, 1 << 30, 1 << 30, 2048, 0, 0,
        W_ih, nullptr, 1 << 30, 4224, 0,
        Z, BB, G4, 512);
    ij_reduce_xfw_kernel<<<2048, 256, 0, stream>>>(Z, XFW);

    for (int t = 0; t < TT; ++t) {
        const int* pop_t = pop + t * BKR;
        ij_emb_kernel<<<256, 256, 0, stream>>>(W_emb, b_emb, pop_t, EMB);

        ij_gemm_f16x3<<<dim3(64, 4, 2), 256, 0, stream>>>(
            EMB, x_f3 + (size_t)t * BKR * 2048, H, 128, 2176, 128, 2048, 2048,
            W_ih + 2048, W_hh, 2176, 4224, 2048,
            Z, G4, 2112);

        ij_lstm_kernel<<<4096, 256, 0, stream>>>(Z, Z1, XFW, BIAS, Cc, H2, C2);

        ij_gemm_f16x3<<<dim3(16, 4, 4), 256, 0, stream>>>(
            H2, nullptr, nullptr, 1 << 30, 1 << 30, 2048, 0, 0,
            W_fc1, nullptr, 1 << 30, 2048, 0,
            Z, HH, 512);
        ij_reduce_fc1_kernel<<<4096, 256, 0, stream>>>(Z, b_fc1, HD);

        ij_gemm_f16x3<<<dim3(4, 4, 16), 256, 0, stream>>>(
            HD, nullptr, nullptr, 1 << 30, 1 << 30, 2048, 0, 0,
            W_out, nullptr, 1 << 30, 2048, 0,
            Z, DD, 128);

        ij_softmax_g_kernel<<<512, 256, 0, stream>>>(
            Z, b_out, mask, pop_t, gum + (size_t)t * BKR * DD,
            Gv, LOGP, LPT, GMAT, GREEDY);

        ij_beam_kernel<<<64, 256, 0, stream>>>(
            GMAT, LPT, GREEDY, pop_t, mask,
            Gv, LOGP, SAMP, OUTS, ENT, WPQ, LGP, ORDER, t);

        ij_permute_kernel<<<4096, 256, 0, stream>>>(H2, C2, ORDER, H, Cc);
    }

    ij_final_kernel<<<25, 256, 0, stream>>>(OUTS, SAMP, ENT, WPQ, LGP, out);
    (void)in_sizes; (void)n_in; (void)out_size;
}